// Round 4
// baseline (460.733 us; speedup 1.0000x reference)
//
#include <hip/hip_runtime.h>
#include <hip/hip_bf16.h>
#include <hip/hip_fp8.h>
#include <math.h>

#define U_CNT 50000
#define I_CNT 50000
#define N_CNT 100000
#define D 64
#define NNZ_CNT 3200000
#define LAYERS 3
#define BATCH 4096
#define L2_REG_F 1e-5f
#define EPS_F 1e-12f

#define NBUCKET 391     // 256 rows per bucket
#define SC_NBLK 256     // scatter blocks (1 per CU), 1024 threads each
#define SC_CHUNK 12500  // NNZ / SC_NBLK
#define BCNT_N (NBUCKET * SC_NBLK)       // 100,096
#define BCNT_NBLK ((BCNT_N + 255) / 256) // 392

typedef __attribute__((ext_vector_type(8))) short short8;
typedef __attribute__((ext_vector_type(4))) float floatx4;
typedef __attribute__((ext_vector_type(2))) float f32x2v;

__device__ __forceinline__ unsigned short f32_to_bf16(float f) {
    unsigned int u = __float_as_uint(f);
    u += 0x7FFFu + ((u >> 16) & 1u);   // round-to-nearest-even
    return (unsigned short)(u >> 16);
}
__device__ __forceinline__ float bf16_to_f32(unsigned short h) {
    return __uint_as_float(((unsigned int)h) << 16);
}
__device__ __forceinline__ float bf16_lo(unsigned int u) {
    return __uint_as_float(u << 16);
}
__device__ __forceinline__ float bf16_hi(unsigned int u) {
    return __uint_as_float(u & 0xFFFF0000u);
}
__device__ __forceinline__ unsigned int pack_bf16(float a, float b) {
    return (unsigned int)f32_to_bf16(a) | ((unsigned int)f32_to_bf16(b) << 16);
}

// ---- fp8 e4m3 (OCP, gfx950) helpers: HW cvt via builtins, header fallback.
// NOTE: the builtins' word-select operand must be an ICE -> template param.
__device__ __forceinline__ unsigned char f32_to_fp8(float v) {
#if __has_builtin(__builtin_amdgcn_cvt_pk_fp8_f32)
    return (unsigned char)(__builtin_amdgcn_cvt_pk_fp8_f32(v, 0.0f, 0, false) & 0xFF);
#else
    __hip_fp8_e4m3 t(v);
    return (unsigned char)t.__x;
#endif
}
template <bool HI>
__device__ __forceinline__ f32x2v fp8x2_to_f32(unsigned int w) {
#if __has_builtin(__builtin_amdgcn_cvt_pk_f32_fp8)
    return __builtin_amdgcn_cvt_pk_f32_fp8((int)w, HI);
#else
    unsigned int s = HI ? (w >> 16) : (w & 0xFFFFu);
    __hip_fp8_e4m3 a, b;
    a.__x = (unsigned char)(s & 0xFF);
    b.__x = (unsigned char)((s >> 8) & 0xFF);
    f32x2v r;
    r.x = (float)a;
    r.y = (float)b;
    return r;
#endif
}

// ---------------- init: one wave per row. all_e[:,0:64] fp32; Ebf bf16;
// Efp8 = e4m3 row-scaled copy (for spmm gathers) + scales[row] = rowmax/224.
__global__ __launch_bounds__(256) void init_E(const float* __restrict__ ue,
                                              const float* __restrict__ ie,
                                              unsigned short* __restrict__ Ebf,
                                              unsigned char* __restrict__ Efp8,
                                              float* __restrict__ scales,
                                              float* __restrict__ all_e) {
    int wid = (blockIdx.x * blockDim.x + threadIdx.x) >> 6;
    int lane = threadIdx.x & 63;
    if (wid >= N_CNT) return;
    size_t base = (size_t)wid * 64;
    float v = (wid < U_CNT) ? ue[base + lane] : ie[base - (size_t)U_CNT * 64 + lane];
    Ebf[base + lane] = f32_to_bf16(v);
    all_e[(size_t)wid * 256 + lane] = v;
    float m = fabsf(v);
#pragma unroll
    for (int off = 32; off >= 1; off >>= 1) m = fmaxf(m, __shfl_xor(m, off, 64));
    m = fmaxf(m, 1e-30f);
    float esc = 224.0f / m;
    Efp8[base + lane] = f32_to_fp8(v * esc);
    if (lane == 0) scales[wid] = m * (1.0f / 224.0f);
}

// ---------------- generic hierarchical exclusive scan (n <= 512*256)
__global__ void scan_p1(const int* __restrict__ in, int* __restrict__ bsums, int n) {
    __shared__ int s[256];
    int t = threadIdx.x;
    int i = blockIdx.x * 256 + t;
    int v = (i < n) ? in[i] : 0;
    s[t] = v;
    __syncthreads();
    for (int off = 128; off >= 1; off >>= 1) {
        if (t < off) s[t] += s[t + off];
        __syncthreads();
    }
    if (t == 0) bsums[blockIdx.x] = s[0];
}

__global__ void scan_p2(int* __restrict__ bsums, int nblk) {
    __shared__ int s[512];
    int t = threadIdx.x;
    int v = (t < nblk) ? bsums[t] : 0;
    s[t] = v;
    __syncthreads();
    for (int off = 1; off < 512; off <<= 1) {
        int x = (t >= off) ? s[t - off] : 0;
        __syncthreads();
        s[t] += x;
        __syncthreads();
    }
    if (t < nblk) bsums[t] = s[t] - v;  // exclusive
}

__global__ void scan_p3(const int* __restrict__ in, const int* __restrict__ bsums,
                        int* __restrict__ out, int n) {
    __shared__ int s[256];
    int t = threadIdx.x;
    int i = blockIdx.x * 256 + t;
    int v = (i < n) ? in[i] : 0;
    s[t] = v;
    __syncthreads();
    for (int off = 1; off < 256; off <<= 1) {
        int x = (t >= off) ? s[t - off] : 0;
        __syncthreads();
        s[t] += x;
        __syncthreads();
    }
    if (i < n) out[i] = s[t] - v + bsums[blockIdx.x];
}

// ---------------- per-block bucket histogram -> bcnt[bucket*SC_NBLK + blk]
__global__ __launch_bounds__(1024) void bucket_hist(const int* __restrict__ rows,
                                                    int* __restrict__ bcnt) {
    __shared__ int h[NBUCKET];
    int blk = blockIdx.x, t = threadIdx.x;
    if (t < NBUCKET) h[t] = 0;
    __syncthreads();
    int s = blk * SC_CHUNK, e = s + SC_CHUNK;
    for (int i = s + t; i < e; i += 1024) atomicAdd(&h[rows[i] >> 8], 1);
    __syncthreads();
    if (t < NBUCKET) bcnt[t * SC_NBLK + blk] = h[t];
}

// ---------------- scatter into per-(bucket,block) EXCLUSIVE regions (LDS cursors)
__global__ __launch_bounds__(1024) void block_scatter(const int* __restrict__ rows,
                                                      const int* __restrict__ cols,
                                                      const float* __restrict__ vals,
                                                      const int* __restrict__ boff,
                                                      float2* __restrict__ bbuf) {
    __shared__ int cur[NBUCKET];
    int blk = blockIdx.x, t = threadIdx.x;
    if (t < NBUCKET) cur[t] = boff[t * SC_NBLK + blk];
    __syncthreads();
    int s = blk * SC_CHUNK, e = s + SC_CHUNK;
    for (int i = s + t; i < e; i += 1024) {
        int r = rows[i];
        int b = r >> 8;
        int p = atomicAdd(&cur[b], 1);
        unsigned int bits = ((unsigned int)(r & 255) << 17) | (unsigned int)cols[i];
        bbuf[p] = make_float2(vals[i], __uint_as_float(bits));
    }
}

// ---------------- per-bucket: LDS rowlocal hist -> LDS scan -> row_ptr ->
// row-sorted packed (4B records: val_unorm15 << 17 | col17).
__global__ __launch_bounds__(1024) void csr_finalize(const float2* __restrict__ bbuf,
                                                     const int* __restrict__ boff,
                                                     int* __restrict__ row_ptr,
                                                     unsigned int* __restrict__ packed) {
    __shared__ int h[256];
    __shared__ int cur[256];
    int b = blockIdx.x, t = threadIdx.x;
    int s = boff[b * SC_NBLK];
    int e = (b == NBUCKET - 1) ? NNZ_CNT : boff[(b + 1) * SC_NBLK];
    if (t < 256) h[t] = 0;
    __syncthreads();
    for (int i = s + t; i < e; i += 1024)
        atomicAdd(&h[__float_as_uint(bbuf[i].y) >> 17], 1);
    __syncthreads();
    int v = (t < 256) ? h[t] : 0;
    for (int off = 1; off < 256; off <<= 1) {   // Hillis-Steele inclusive scan (t<256)
        int x = (t >= off && t < 256) ? h[t - off] : 0;
        __syncthreads();
        if (t < 256) h[t] += x;
        __syncthreads();
    }
    if (t < 256) {
        int start = s + h[t] - v;  // exclusive + bucket base
        int row = (b << 8) + t;
        if (row < N_CNT) row_ptr[row] = start;
        cur[t] = start;
        if (b == 0 && t == 0) row_ptr[N_CNT] = NNZ_CNT;
    }
    __syncthreads();
    for (int i = s + t; i < e; i += 1024) {
        float2 rec = bbuf[i];
        unsigned int bits = __float_as_uint(rec.y);
        int p = atomicAdd(&cur[bits >> 17], 1);
        unsigned int q = (unsigned int)(rec.x * 32767.0f + 0.5f);  // val in [0,1)
        packed[p] = (q << 17) | (bits & 0x1FFFFu);
    }
}

// ---------------- SpMM: one wave per row; 8 edge slots x 8 lanes.
// v3: fp8 gather. Each edge's E row is 64B (ONE cache line vs two at bf16):
// halves L2 line-lookups and bytes on the saturated random-gather path, and
// the 6.4MB table sits closer to the 4MB per-XCD L2. Per-row f32 scale
// (L2-resident 400KB) restores dynamic range. packed is 4B/edge (val unorm15).
__global__ __launch_bounds__(256) void spmm_fp8(const unsigned int* __restrict__ packed,
                                                const int* __restrict__ row_ptr,
                                                const unsigned char* __restrict__ Efp8,
                                                const float* __restrict__ scales,
                                                unsigned short* __restrict__ Lm) {
    int wid = (blockIdx.x * blockDim.x + threadIdx.x) >> 6;
    int lane = threadIdx.x & 63;
    if (wid >= N_CNT) return;
    int s = row_ptr[wid];
    int e = row_ptr[wid + 1];
    int eidx = lane >> 3;      // edge slot [0,8)
    int dlane = lane & 7;      // 8 dims each (dlane*8 .. +7)
    float a0 = 0.f, a1 = 0.f, a2 = 0.f, a3 = 0.f;
    float a4 = 0.f, a5 = 0.f, a6 = 0.f, a7 = 0.f;
    int i = s + eidx;
    unsigned int u = (i < e) ? packed[i] : 0u;   // col 0, val 0 -> contributes 0
    while (i < e) {
        int inext = i + 8;
        unsigned int un = (inext < e) ? packed[inext] : 0u;
        int c = (int)(u & 0x1FFFFu);
        float sc = scales[c];
        uint2 g = *(const uint2*)(Efp8 + ((size_t)c << 6) + (dlane << 3));
        float vs = (float)(u >> 17) * (1.0f / 32767.0f) * sc;
        f32x2v p0 = fp8x2_to_f32<false>(g.x);
        f32x2v p1 = fp8x2_to_f32<true>(g.x);
        f32x2v p2 = fp8x2_to_f32<false>(g.y);
        f32x2v p3 = fp8x2_to_f32<true>(g.y);
        a0 += vs * p0.x; a1 += vs * p0.y;
        a2 += vs * p1.x; a3 += vs * p1.y;
        a4 += vs * p2.x; a5 += vs * p2.y;
        a6 += vs * p3.x; a7 += vs * p3.y;
        u = un;
        i = inext;
    }
    // combine the 8 edge slots: lanes with same dlane differ by 8/16/32 in lane id
#pragma unroll
    for (int off = 32; off >= 8; off >>= 1) {
        a0 += __shfl_xor(a0, off, 64); a1 += __shfl_xor(a1, off, 64);
        a2 += __shfl_xor(a2, off, 64); a3 += __shfl_xor(a3, off, 64);
        a4 += __shfl_xor(a4, off, 64); a5 += __shfl_xor(a5, off, 64);
        a6 += __shfl_xor(a6, off, 64); a7 += __shfl_xor(a7, off, 64);
    }
    if (eidx == 0) {  // lanes 0..7 write 16B each -> 128B bf16 row
        unsigned int* dst = (unsigned int*)(Lm + (size_t)wid * D + dlane * 8);
        *(uint4*)dst = make_uint4(pack_bf16(a0, a1), pack_bf16(a2, a3),
                                  pack_bf16(a4, a5), pack_bf16(a6, a7));
    }
}

// ---------------- fused layer via MFMA: Y = leaky([Lm+E | Lm*E] @ [W1;W2] + b1+b2)
// un-normalized Y -> Ebf (bf16) and (layer<2) Efp8+scales for the next spmm;
// row-normalized Y -> all_e[:, (layer+1)*64:...]
#define AP 136  // A/B^T row stride in shorts (128 + 8 pad -> 4-bank stagger)
__global__ __launch_bounds__(256) void layer_fused_mfma(const unsigned short* __restrict__ Lm,
                                                        unsigned short* __restrict__ Ebf,
                                                        unsigned char* __restrict__ Efp8,
                                                        float* __restrict__ scales,
                                                        const float* __restrict__ W1,
                                                        const float* __restrict__ b1,
                                                        const float* __restrict__ W2,
                                                        const float* __restrict__ b2,
                                                        float* __restrict__ all_e, int layer) {
    __shared__ unsigned short sBt[64 * AP];    // B^T[n][k] bf16 (k<64: W1, k>=64: W2)
    __shared__ float sBias[64];
    __shared__ unsigned short sA[4][16 * AP];  // per-wave A staging (also fp8 out staging)

    int t = threadIdx.x;
    for (int i = t; i < 4096; i += 256) {
        int k = i >> 6, n = i & 63;
        sBt[n * AP + k] = f32_to_bf16(W1[i]);
        sBt[n * AP + 64 + k] = f32_to_bf16(W2[i]);
    }
    if (t < 64) sBias[t] = b1[t] + b2[t];
    __syncthreads();

    int w = t >> 6, lane = t & 63;
    int quad = lane >> 4, l16 = lane & 15;

    short8 bfrag[4][4];
#pragma unroll
    for (int ks = 0; ks < 4; ks++)
#pragma unroll
        for (int ct = 0; ct < 4; ct++)
            bfrag[ks][ct] = *(const short8*)&sBt[(ct * 16 + l16) * AP + ks * 32 + quad * 8];

    float bias[4];
#pragma unroll
    for (int ct = 0; ct < 4; ct++) bias[ct] = sBias[ct * 16 + l16];

    unsigned short* A = sA[w];
    int col_off = (layer + 1) * 64;
    int nwaves = gridDim.x * 4;

    for (int tile = blockIdx.x * 4 + w; tile < N_CNT / 16; tile += nwaves) {
        int rbase = tile * 16;
#pragma unroll
        for (int p = 0; p < 4; p++) {
            int r = p * 4 + quad;
            int c = l16 * 4;
            uint2 lw = *(const uint2*)(Lm + (size_t)(rbase + r) * 64 + c);
            float l0 = bf16_lo(lw.x), l1 = bf16_hi(lw.x);
            float l2 = bf16_lo(lw.y), l3 = bf16_hi(lw.y);
            ushort4 eh = *(const ushort4*)(Ebf + (size_t)(rbase + r) * 64 + c);
            float e0 = bf16_to_f32(eh.x), e1 = bf16_to_f32(eh.y);
            float e2 = bf16_to_f32(eh.z), e3 = bf16_to_f32(eh.w);
            *(uint2*)&A[r * AP + c] = make_uint2(pack_bf16(l0 + e0, l1 + e1),
                                                pack_bf16(l2 + e2, l3 + e3));
            *(uint2*)&A[r * AP + 64 + c] = make_uint2(pack_bf16(l0 * e0, l1 * e1),
                                                      pack_bf16(l2 * e2, l3 * e3));
        }
        floatx4 acc[4];
#pragma unroll
        for (int ct = 0; ct < 4; ct++) {
            acc[ct][0] = bias[ct]; acc[ct][1] = bias[ct];
            acc[ct][2] = bias[ct]; acc[ct][3] = bias[ct];
        }
#pragma unroll
        for (int ks = 0; ks < 4; ks++) {
            short8 af = *(const short8*)&A[l16 * AP + ks * 32 + quad * 8];
#pragma unroll
            for (int ct = 0; ct < 4; ct++)
                acc[ct] = __builtin_amdgcn_mfma_f32_16x16x32_bf16(af, bfrag[ks][ct], acc[ct], 0, 0, 0);
        }
        float y[4][4];
        float ssq[4] = {0.f, 0.f, 0.f, 0.f};
        float rmx[4] = {0.f, 0.f, 0.f, 0.f};
#pragma unroll
        for (int ct = 0; ct < 4; ct++)
#pragma unroll
            for (int reg = 0; reg < 4; reg++) {
                float v = acc[ct][reg];
                v = (v > 0.f) ? v : 0.2f * v;
                y[ct][reg] = v;
                ssq[reg] += v * v;
                rmx[reg] = fmaxf(rmx[reg], fabsf(v));
            }
#pragma unroll
        for (int reg = 0; reg < 4; reg++) {
            float ss = ssq[reg];
            ss += __shfl_xor(ss, 1, 64);
            ss += __shfl_xor(ss, 2, 64);
            ss += __shfl_xor(ss, 4, 64);
            ss += __shfl_xor(ss, 8, 64);
            ssq[reg] = fmaxf(sqrtf(ss), EPS_F);
            float mm = rmx[reg];
            mm = fmaxf(mm, __shfl_xor(mm, 1, 64));
            mm = fmaxf(mm, __shfl_xor(mm, 2, 64));
            mm = fmaxf(mm, __shfl_xor(mm, 4, 64));
            mm = fmaxf(mm, __shfl_xor(mm, 8, 64));
            rmx[reg] = fmaxf(mm, 1e-30f);
        }
#pragma unroll
        for (int reg = 0; reg < 4; reg++) {
            int row = rbase + quad * 4 + reg;
            float inv = 1.0f / ssq[reg];
#pragma unroll
            for (int ct = 0; ct < 4; ct++) {
                int col = ct * 16 + l16;
                float v = y[ct][reg];
                Ebf[(size_t)row * 64 + col] = f32_to_bf16(v);
                all_e[(size_t)row * 256 + col_off + col] = v * inv;
            }
        }
        if (layer < 2) {
            // fp8 row-scaled copy for the next spmm's gathers, staged via LDS
            unsigned char* sb = (unsigned char*)A;  // per-wave, A already consumed
#pragma unroll
            for (int reg = 0; reg < 4; reg++) {
                float esc = 224.0f / rmx[reg];
                int rl = quad * 4 + reg;
#pragma unroll
                for (int ct = 0; ct < 4; ct++)
                    sb[rl * 64 + ct * 16 + l16] = f32_to_fp8(y[ct][reg] * esc);
            }
            if (l16 == 0) {
#pragma unroll
                for (int reg = 0; reg < 4; reg++)
                    scales[rbase + quad * 4 + reg] = rmx[reg] * (1.0f / 224.0f);
            }
            __builtin_amdgcn_wave_barrier();  // LDS staging is wave-private; no fence needed beyond this
            uint4 ov = *(const uint4*)(sb + lane * 16);   // 16 rows x 64B = 1KB/wave
            *(uint4*)(Efp8 + (size_t)rbase * 64 + lane * 16) = ov;
        }
    }
}

// ---------------- scoring: one wave per sample, per-sample partials (NO atomics)
__device__ __forceinline__ float dot4(float4 a, float4 b) {
    return a.x * b.x + a.y * b.y + a.z * b.z + a.w * b.w;
}

__global__ __launch_bounds__(256) void score_kernel(const float* __restrict__ all_e,
                                                    const int* __restrict__ users,
                                                    const int* __restrict__ pos,
                                                    const int* __restrict__ neg,
                                                    float4* __restrict__ partials) {
    int wid = (blockIdx.x * blockDim.x + threadIdx.x) >> 6;
    int lane = threadIdx.x & 63;
    if (wid >= BATCH) return;
    int ui = users[wid];
    int pi = pos[wid];
    int ni = neg[wid];
    const float4* uv4 = (const float4*)(all_e + (size_t)ui * 256);
    const float4* pv4 = (const float4*)(all_e + (size_t)pi * 256);
    const float4* nv4 = (const float4*)(all_e + (size_t)ni * 256);
    float4 uv = uv4[lane];
    float4 pv = pv4[lane];
    float4 nv = nv4[lane];
    float s_up = dot4(uv, pv);
    float s_un = dot4(uv, nv);
    float s_uu = dot4(uv, uv);
    float s_pp = dot4(pv, pv);
    float s_nn = dot4(nv, nv);
#pragma unroll
    for (int off = 32; off >= 1; off >>= 1) {
        s_up += __shfl_xor(s_up, off, 64);
        s_un += __shfl_xor(s_un, off, 64);
        s_uu += __shfl_xor(s_uu, off, 64);
        s_pp += __shfl_xor(s_pp, off, 64);
        s_nn += __shfl_xor(s_nn, off, 64);
    }
    if (lane == 0) {
        float x = s_up - s_un;
        float ls = fminf(x, 0.f) - log1pf(expf(-fabsf(x)));  // log_sigmoid
        partials[wid] = make_float4(-ls, s_uu, s_pp, s_nn);
    }
}

// single-block tree reduction over 4096 float4 partials + final scalar
__global__ __launch_bounds__(256) void reduce_finalize(const float4* __restrict__ partials,
                                                       float* __restrict__ out) {
    __shared__ float4 s[256];
    int t = threadIdx.x;
    float4 a = make_float4(0.f, 0.f, 0.f, 0.f);
    for (int i = t; i < BATCH; i += 256) {
        float4 p = partials[i];
        a.x += p.x; a.y += p.y; a.z += p.z; a.w += p.w;
    }
    s[t] = a;
    __syncthreads();
    for (int off = 128; off >= 1; off >>= 1) {
        if (t < off) {
            s[t].x += s[t + off].x;
            s[t].y += s[t + off].y;
            s[t].z += s[t + off].z;
            s[t].w += s[t + off].w;
        }
        __syncthreads();
    }
    if (t == 0) {
        float bpr = s[0].x / (float)BATCH;
        float l2norm = (s[0].y + s[0].z + sqrtf(s[0].w)) * 0.5f;
        out[0] = bpr + L2_REG_F * l2norm / (float)BATCH;
    }
}

extern "C" void kernel_launch(void* const* d_in, const int* in_sizes, int n_in,
                              void* d_out, int out_size, void* d_ws, size_t ws_size,
                              hipStream_t stream) {
    const int* users = (const int*)d_in[0];
    const int* pos_items = (const int*)d_in[1];
    const int* neg_items = (const int*)d_in[2];
    const int* rows = (const int*)d_in[3];
    const int* cols = (const int*)d_in[4];
    const float* vals = (const float*)d_in[5];
    const float* user_embed = (const float*)d_in[6];
    const float* item_embed = (const float*)d_in[7];
    const float* W1 = (const float*)d_in[8];
    const float* b1 = (const float*)d_in[9];
    const float* W2 = (const float*)d_in[10];
    const float* b2 = (const float*)d_in[11];
    float* out = (float*)d_out;

    char* ws = (char*)d_ws;
    // workspace layout: total ~148.5 MB (was 154.5; packed 8B->4B freed room
    // for the 6.4MB fp8 gather table + 0.4MB row scales)
    size_t off_alle = 0;                                     // 102,400,000
    size_t off_packed = off_alle + (size_t)N_CNT * 256 * 4;  // 12,800,000 (4B recs)
    size_t off_Ebf = off_packed + (size_t)NNZ_CNT * 4;       // 12,800,000
    size_t off_Efp8 = off_Ebf + (size_t)N_CNT * D * 2;       // 6,400,000
    size_t off_scales = off_Efp8 + (size_t)N_CNT * D;        // 400,000
    size_t off_Lm = off_scales + (size_t)N_CNT * 4;          // 12,800,000 (bf16)
    size_t off_rowptr = off_Lm + (size_t)N_CNT * D * 2;      // 400,128
    size_t off_blkB = off_rowptr + 400128;                   // 2,048
    size_t off_bcnt = off_blkB + 2048;                       // 400,384
    size_t off_part = off_bcnt + 400384;                     // 65,536

    float* all_e = (float*)(ws + off_alle);
    float2* bbuf = (float2*)(ws + off_alle);   // aliases all_e; dead before init_E runs
    unsigned int* packed = (unsigned int*)(ws + off_packed);
    unsigned short* Ebf = (unsigned short*)(ws + off_Ebf);
    unsigned char* Efp8 = (unsigned char*)(ws + off_Efp8);
    float* scales = (float*)(ws + off_scales);
    unsigned short* Lm = (unsigned short*)(ws + off_Lm);
    int* row_ptr = (int*)(ws + off_rowptr);
    int* blkB = (int*)(ws + off_blkB);
    int* bcnt = (int*)(ws + off_bcnt);
    float4* partials = (float4*)(ws + off_part);

    // bucketed multisplit with exclusive per-(bucket,block) regions
    bucket_hist<<<SC_NBLK, 1024, 0, stream>>>(rows, bcnt);
    scan_p1<<<BCNT_NBLK, 256, 0, stream>>>(bcnt, blkB, BCNT_N);
    scan_p2<<<1, 512, 0, stream>>>(blkB, BCNT_NBLK);
    scan_p3<<<BCNT_NBLK, 256, 0, stream>>>(bcnt, blkB, bcnt, BCNT_N);  // in-place
    block_scatter<<<SC_NBLK, 1024, 0, stream>>>(rows, cols, vals, bcnt, bbuf);
    csr_finalize<<<NBUCKET, 1024, 0, stream>>>(bbuf, bcnt, row_ptr, packed);

    // embeddings (after csr_finalize: bbuf aliases all_e)
    init_E<<<(N_CNT * 64) / 256, 256, 0, stream>>>(user_embed, item_embed, Ebf, Efp8,
                                                   scales, all_e);

    for (int l = 0; l < LAYERS; l++) {
        spmm_fp8<<<(N_CNT * 64) / 256, 256, 0, stream>>>(packed, row_ptr, Efp8, scales, Lm);
        layer_fused_mfma<<<784, 256, 0, stream>>>(Lm, Ebf, Efp8, scales,
                                                  W1 + (size_t)l * 4096, b1 + (size_t)l * 64,
                                                  W2 + (size_t)l * 4096, b2 + (size_t)l * 64,
                                                  all_e, l);
    }

    score_kernel<<<(BATCH * 64) / 256, 256, 0, stream>>>(all_e, users, pos_items, neg_items,
                                                         partials);
    reduce_finalize<<<1, 256, 0, stream>>>(partials, out);
}

// Round 6
// 449.408 us; speedup vs baseline: 1.0252x; 1.0252x over previous
//
#include <hip/hip_runtime.h>
#include <hip/hip_bf16.h>
#include <hip/hip_fp8.h>
#include <math.h>

#define U_CNT 50000
#define I_CNT 50000
#define N_CNT 100000
#define D 64
#define NNZ_CNT 3200000
#define LAYERS 3
#define BATCH 4096
#define L2_REG_F 1e-5f
#define EPS_F 1e-12f

#define NBUCKET 391     // 256 rows per bucket
#define SC_NBLK 256     // scatter blocks (1 per CU), 1024 threads each
#define SC_CHUNK 12500  // NNZ / SC_NBLK
#define BCNT_N (NBUCKET * SC_NBLK)       // 100,096
#define BCNT_NBLK ((BCNT_N + 255) / 256) // 392

typedef __attribute__((ext_vector_type(8))) short short8;
typedef __attribute__((ext_vector_type(4))) float floatx4;
typedef __attribute__((ext_vector_type(2))) float f32x2v;

__device__ __forceinline__ unsigned short f32_to_bf16(float f) {
    unsigned int u = __float_as_uint(f);
    u += 0x7FFFu + ((u >> 16) & 1u);   // round-to-nearest-even
    return (unsigned short)(u >> 16);
}
__device__ __forceinline__ float bf16_to_f32(unsigned short h) {
    return __uint_as_float(((unsigned int)h) << 16);
}
__device__ __forceinline__ float bf16_lo(unsigned int u) {
    return __uint_as_float(u << 16);
}
__device__ __forceinline__ float bf16_hi(unsigned int u) {
    return __uint_as_float(u & 0xFFFF0000u);
}
__device__ __forceinline__ unsigned int pack_bf16(float a, float b) {
    return (unsigned int)f32_to_bf16(a) | ((unsigned int)f32_to_bf16(b) << 16);
}

// ---- fp8 e4m3 (OCP, gfx950) helpers. UNSCALED but CLAMPED to +-448:
// the HW cvt does NOT saturate — |v| > 448 encodes NaN (0x7F) and poisons the
// whole pipeline (Round-5 failure: layer-2 activations' tail exceeded 448).
// Clamp cost: 2 VALU ops per encode; clamped entries are rare tail values and
// rows are later L2-normalized, so the induced error is negligible.
__device__ __forceinline__ unsigned char f32_to_fp8(float v) {
    v = fminf(fmaxf(v, -448.0f), 448.0f);
#if __has_builtin(__builtin_amdgcn_cvt_pk_fp8_f32)
    return (unsigned char)(__builtin_amdgcn_cvt_pk_fp8_f32(v, 0.0f, 0, false) & 0xFF);
#else
    __hip_fp8_e4m3 t(v);
    return (unsigned char)t.__x;
#endif
}
template <bool HI>
__device__ __forceinline__ f32x2v fp8x2_to_f32(unsigned int w) {
#if __has_builtin(__builtin_amdgcn_cvt_pk_f32_fp8)
    return __builtin_amdgcn_cvt_pk_f32_fp8((int)w, HI);
#else
    unsigned int s = HI ? (w >> 16) : (w & 0xFFFFu);
    __hip_fp8_e4m3 a, b;
    a.__x = (unsigned char)(s & 0xFF);
    b.__x = (unsigned char)((s >> 8) & 0xFF);
    f32x2v r;
    r.x = (float)a;
    r.y = (float)b;
    return r;
#endif
}

// ---------------- init: all_e[:,0:64] fp32; Ebf bf16; Efp8 e4m3 (unscaled)
__global__ void init_E(const float* __restrict__ ue, const float* __restrict__ ie,
                       unsigned short* __restrict__ Ebf, unsigned char* __restrict__ Efp8,
                       float* __restrict__ all_e) {
    int tid = blockIdx.x * blockDim.x + threadIdx.x;
    if (tid >= N_CNT * D) return;
    int row = tid >> 6;
    int d = tid & 63;
    float v = (row < U_CNT) ? ue[tid] : ie[tid - U_CNT * D];
    Ebf[tid] = f32_to_bf16(v);
    Efp8[tid] = f32_to_fp8(v);
    all_e[(size_t)row * 256 + d] = v;
}

// ---------------- generic hierarchical exclusive scan (n <= 512*256)
__global__ void scan_p1(const int* __restrict__ in, int* __restrict__ bsums, int n) {
    __shared__ int s[256];
    int t = threadIdx.x;
    int i = blockIdx.x * 256 + t;
    int v = (i < n) ? in[i] : 0;
    s[t] = v;
    __syncthreads();
    for (int off = 128; off >= 1; off >>= 1) {
        if (t < off) s[t] += s[t + off];
        __syncthreads();
    }
    if (t == 0) bsums[blockIdx.x] = s[0];
}

__global__ void scan_p2(int* __restrict__ bsums, int nblk) {
    __shared__ int s[512];
    int t = threadIdx.x;
    int v = (t < nblk) ? bsums[t] : 0;
    s[t] = v;
    __syncthreads();
    for (int off = 1; off < 512; off <<= 1) {
        int x = (t >= off) ? s[t - off] : 0;
        __syncthreads();
        s[t] += x;
        __syncthreads();
    }
    if (t < nblk) bsums[t] = s[t] - v;  // exclusive
}

__global__ void scan_p3(const int* __restrict__ in, const int* __restrict__ bsums,
                        int* __restrict__ out, int n) {
    __shared__ int s[256];
    int t = threadIdx.x;
    int i = blockIdx.x * 256 + t;
    int v = (i < n) ? in[i] : 0;
    s[t] = v;
    __syncthreads();
    for (int off = 1; off < 256; off <<= 1) {
        int x = (t >= off) ? s[t - off] : 0;
        __syncthreads();
        s[t] += x;
        __syncthreads();
    }
    if (i < n) out[i] = s[t] - v + bsums[blockIdx.x];
}

// ---------------- per-block bucket histogram -> bcnt[bucket*SC_NBLK + blk]
__global__ __launch_bounds__(1024) void bucket_hist(const int* __restrict__ rows,
                                                    int* __restrict__ bcnt) {
    __shared__ int h[NBUCKET];
    int blk = blockIdx.x, t = threadIdx.x;
    if (t < NBUCKET) h[t] = 0;
    __syncthreads();
    int s = blk * SC_CHUNK, e = s + SC_CHUNK;
    for (int i = s + t; i < e; i += 1024) atomicAdd(&h[rows[i] >> 8], 1);
    __syncthreads();
    if (t < NBUCKET) bcnt[t * SC_NBLK + blk] = h[t];
}

// ---------------- scatter into per-(bucket,block) EXCLUSIVE regions (LDS cursors)
__global__ __launch_bounds__(1024) void block_scatter(const int* __restrict__ rows,
                                                      const int* __restrict__ cols,
                                                      const float* __restrict__ vals,
                                                      const int* __restrict__ boff,
                                                      float2* __restrict__ bbuf) {
    __shared__ int cur[NBUCKET];
    int blk = blockIdx.x, t = threadIdx.x;
    if (t < NBUCKET) cur[t] = boff[t * SC_NBLK + blk];
    __syncthreads();
    int s = blk * SC_CHUNK, e = s + SC_CHUNK;
    for (int i = s + t; i < e; i += 1024) {
        int r = rows[i];
        int b = r >> 8;
        int p = atomicAdd(&cur[b], 1);
        unsigned int bits = ((unsigned int)(r & 255) << 17) | (unsigned int)cols[i];
        bbuf[p] = make_float2(vals[i], __uint_as_float(bits));
    }
}

// ---------------- per-bucket: LDS rowlocal hist -> LDS scan -> row_ptr ->
// row-sorted packed (4B records: val_unorm15 << 17 | col17).
__global__ __launch_bounds__(1024) void csr_finalize(const float2* __restrict__ bbuf,
                                                     const int* __restrict__ boff,
                                                     int* __restrict__ row_ptr,
                                                     unsigned int* __restrict__ packed) {
    __shared__ int h[256];
    __shared__ int cur[256];
    int b = blockIdx.x, t = threadIdx.x;
    int s = boff[b * SC_NBLK];
    int e = (b == NBUCKET - 1) ? NNZ_CNT : boff[(b + 1) * SC_NBLK];
    if (t < 256) h[t] = 0;
    __syncthreads();
    for (int i = s + t; i < e; i += 1024)
        atomicAdd(&h[__float_as_uint(bbuf[i].y) >> 17], 1);
    __syncthreads();
    int v = (t < 256) ? h[t] : 0;
    for (int off = 1; off < 256; off <<= 1) {   // Hillis-Steele inclusive scan (t<256)
        int x = (t >= off && t < 256) ? h[t - off] : 0;
        __syncthreads();
        if (t < 256) h[t] += x;
        __syncthreads();
    }
    if (t < 256) {
        int start = s + h[t] - v;  // exclusive + bucket base
        int row = (b << 8) + t;
        if (row < N_CNT) row_ptr[row] = start;
        cur[t] = start;
        if (b == 0 && t == 0) row_ptr[N_CNT] = NNZ_CNT;
    }
    __syncthreads();
    for (int i = s + t; i < e; i += 1024) {
        float2 rec = bbuf[i];
        unsigned int bits = __float_as_uint(rec.y);
        int p = atomicAdd(&cur[bits >> 17], 1);
        unsigned int q = (unsigned int)(rec.x * 32767.0f + 0.5f);  // val in [0,1)
        packed[p] = (q << 17) | (bits & 0x1FFFFu);
    }
}

// ---------------- SpMM: one wave per row; 8 edge slots x 8 lanes.
// v6: UNSCALED (clamped) fp8 gather. Per wave-iter: ~8.5 L2 line-lookups
// (8 gather rows x 64B + sequential packed) vs 16-16.5 in bf16/scaled-fp8
// versions. 2 VMEM instructions per edge-slot iteration.
__global__ __launch_bounds__(256) void spmm_fp8(const unsigned int* __restrict__ packed,
                                                const int* __restrict__ row_ptr,
                                                const unsigned char* __restrict__ Efp8,
                                                unsigned short* __restrict__ Lm) {
    int wid = (blockIdx.x * blockDim.x + threadIdx.x) >> 6;
    int lane = threadIdx.x & 63;
    if (wid >= N_CNT) return;
    int s = row_ptr[wid];
    int e = row_ptr[wid + 1];
    int eidx = lane >> 3;      // edge slot [0,8)
    int dlane = lane & 7;      // 8 dims each (dlane*8 .. +7)
    float a0 = 0.f, a1 = 0.f, a2 = 0.f, a3 = 0.f;
    float a4 = 0.f, a5 = 0.f, a6 = 0.f, a7 = 0.f;
    int i = s + eidx;
    unsigned int u = (i < e) ? packed[i] : 0u;   // col 0, val 0 -> contributes 0
    while (i < e) {
        int inext = i + 8;
        unsigned int un = (inext < e) ? packed[inext] : 0u;
        int c = (int)(u & 0x1FFFFu);
        uint2 g = *(const uint2*)(Efp8 + ((size_t)c << 6) + (dlane << 3));
        float vs = (float)(u >> 17) * (1.0f / 32767.0f);
        f32x2v p0 = fp8x2_to_f32<false>(g.x);
        f32x2v p1 = fp8x2_to_f32<true>(g.x);
        f32x2v p2 = fp8x2_to_f32<false>(g.y);
        f32x2v p3 = fp8x2_to_f32<true>(g.y);
        a0 += vs * p0.x; a1 += vs * p0.y;
        a2 += vs * p1.x; a3 += vs * p1.y;
        a4 += vs * p2.x; a5 += vs * p2.y;
        a6 += vs * p3.x; a7 += vs * p3.y;
        u = un;
        i = inext;
    }
    // combine the 8 edge slots: lanes with same dlane differ by 8/16/32 in lane id
#pragma unroll
    for (int off = 32; off >= 8; off >>= 1) {
        a0 += __shfl_xor(a0, off, 64); a1 += __shfl_xor(a1, off, 64);
        a2 += __shfl_xor(a2, off, 64); a3 += __shfl_xor(a3, off, 64);
        a4 += __shfl_xor(a4, off, 64); a5 += __shfl_xor(a5, off, 64);
        a6 += __shfl_xor(a6, off, 64); a7 += __shfl_xor(a7, off, 64);
    }
    if (eidx == 0) {  // lanes 0..7 write 16B each -> 128B bf16 row
        unsigned int* dst = (unsigned int*)(Lm + (size_t)wid * D + dlane * 8);
        *(uint4*)dst = make_uint4(pack_bf16(a0, a1), pack_bf16(a2, a3),
                                  pack_bf16(a4, a5), pack_bf16(a6, a7));
    }
}

// ---------------- fused layer via MFMA: Y = leaky([Lm+E | Lm*E] @ [W1;W2] + b1+b2)
// un-normalized Y -> Ebf (bf16) and (layer<2) Efp8 for the next spmm;
// row-normalized Y -> all_e[:, (layer+1)*64:...]
#define AP 136  // A/B^T row stride in shorts (128 + 8 pad -> 4-bank stagger)
__global__ __launch_bounds__(256) void layer_fused_mfma(const unsigned short* __restrict__ Lm,
                                                        unsigned short* __restrict__ Ebf,
                                                        unsigned char* __restrict__ Efp8,
                                                        const float* __restrict__ W1,
                                                        const float* __restrict__ b1,
                                                        const float* __restrict__ W2,
                                                        const float* __restrict__ b2,
                                                        float* __restrict__ all_e, int layer) {
    __shared__ unsigned short sBt[64 * AP];    // B^T[n][k] bf16 (k<64: W1, k>=64: W2)
    __shared__ float sBias[64];
    __shared__ unsigned short sA[4][16 * AP];  // per-wave A staging (also fp8 out staging)

    int t = threadIdx.x;
    for (int i = t; i < 4096; i += 256) {
        int k = i >> 6, n = i & 63;
        sBt[n * AP + k] = f32_to_bf16(W1[i]);
        sBt[n * AP + 64 + k] = f32_to_bf16(W2[i]);
    }
    if (t < 64) sBias[t] = b1[t] + b2[t];
    __syncthreads();

    int w = t >> 6, lane = t & 63;
    int quad = lane >> 4, l16 = lane & 15;

    short8 bfrag[4][4];
#pragma unroll
    for (int ks = 0; ks < 4; ks++)
#pragma unroll
        for (int ct = 0; ct < 4; ct++)
            bfrag[ks][ct] = *(const short8*)&sBt[(ct * 16 + l16) * AP + ks * 32 + quad * 8];

    float bias[4];
#pragma unroll
    for (int ct = 0; ct < 4; ct++) bias[ct] = sBias[ct * 16 + l16];

    unsigned short* A = sA[w];
    int col_off = (layer + 1) * 64;
    int nwaves = gridDim.x * 4;

    for (int tile = blockIdx.x * 4 + w; tile < N_CNT / 16; tile += nwaves) {
        int rbase = tile * 16;
#pragma unroll
        for (int p = 0; p < 4; p++) {
            int r = p * 4 + quad;
            int c = l16 * 4;
            uint2 lw = *(const uint2*)(Lm + (size_t)(rbase + r) * 64 + c);
            float l0 = bf16_lo(lw.x), l1 = bf16_hi(lw.x);
            float l2 = bf16_lo(lw.y), l3 = bf16_hi(lw.y);
            ushort4 eh = *(const ushort4*)(Ebf + (size_t)(rbase + r) * 64 + c);
            float e0 = bf16_to_f32(eh.x), e1 = bf16_to_f32(eh.y);
            float e2 = bf16_to_f32(eh.z), e3 = bf16_to_f32(eh.w);
            *(uint2*)&A[r * AP + c] = make_uint2(pack_bf16(l0 + e0, l1 + e1),
                                                pack_bf16(l2 + e2, l3 + e3));
            *(uint2*)&A[r * AP + 64 + c] = make_uint2(pack_bf16(l0 * e0, l1 * e1),
                                                      pack_bf16(l2 * e2, l3 * e3));
        }
        floatx4 acc[4];
#pragma unroll
        for (int ct = 0; ct < 4; ct++) {
            acc[ct][0] = bias[ct]; acc[ct][1] = bias[ct];
            acc[ct][2] = bias[ct]; acc[ct][3] = bias[ct];
        }
#pragma unroll
        for (int ks = 0; ks < 4; ks++) {
            short8 af = *(const short8*)&A[l16 * AP + ks * 32 + quad * 8];
#pragma unroll
            for (int ct = 0; ct < 4; ct++)
                acc[ct] = __builtin_amdgcn_mfma_f32_16x16x32_bf16(af, bfrag[ks][ct], acc[ct], 0, 0, 0);
        }
        float y[4][4];
        float ssq[4] = {0.f, 0.f, 0.f, 0.f};
#pragma unroll
        for (int ct = 0; ct < 4; ct++)
#pragma unroll
            for (int reg = 0; reg < 4; reg++) {
                float v = acc[ct][reg];
                v = (v > 0.f) ? v : 0.2f * v;
                y[ct][reg] = v;
                ssq[reg] += v * v;
            }
#pragma unroll
        for (int reg = 0; reg < 4; reg++) {
            float ss = ssq[reg];
            ss += __shfl_xor(ss, 1, 64);
            ss += __shfl_xor(ss, 2, 64);
            ss += __shfl_xor(ss, 4, 64);
            ss += __shfl_xor(ss, 8, 64);
            ssq[reg] = fmaxf(sqrtf(ss), EPS_F);
        }
#pragma unroll
        for (int reg = 0; reg < 4; reg++) {
            int row = rbase + quad * 4 + reg;
            float inv = 1.0f / ssq[reg];
#pragma unroll
            for (int ct = 0; ct < 4; ct++) {
                int col = ct * 16 + l16;
                float v = y[ct][reg];
                Ebf[(size_t)row * 64 + col] = f32_to_bf16(v);
                all_e[(size_t)row * 256 + col_off + col] = v * inv;
            }
        }
        if (layer < 2) {
            // fp8 copy for the next spmm's gathers, staged via per-wave LDS
            unsigned char* sb = (unsigned char*)A;  // A already consumed
#pragma unroll
            for (int reg = 0; reg < 4; reg++) {
                int rl = quad * 4 + reg;
#pragma unroll
                for (int ct = 0; ct < 4; ct++)
                    sb[rl * 64 + ct * 16 + l16] = f32_to_fp8(y[ct][reg]);
            }
            __builtin_amdgcn_wave_barrier();
            uint4 ov = *(const uint4*)(sb + lane * 16);   // 16 rows x 64B = 1KB/wave
            *(uint4*)(Efp8 + (size_t)rbase * 64 + lane * 16) = ov;
        }
    }
}

// ---------------- scoring: one wave per sample, per-sample partials (NO atomics)
__device__ __forceinline__ float dot4(float4 a, float4 b) {
    return a.x * b.x + a.y * b.y + a.z * b.z + a.w * b.w;
}

__global__ __launch_bounds__(256) void score_kernel(const float* __restrict__ all_e,
                                                    const int* __restrict__ users,
                                                    const int* __restrict__ pos,
                                                    const int* __restrict__ neg,
                                                    float4* __restrict__ partials) {
    int wid = (blockIdx.x * blockDim.x + threadIdx.x) >> 6;
    int lane = threadIdx.x & 63;
    if (wid >= BATCH) return;
    int ui = users[wid];
    int pi = pos[wid];
    int ni = neg[wid];
    const float4* uv4 = (const float4*)(all_e + (size_t)ui * 256);
    const float4* pv4 = (const float4*)(all_e + (size_t)pi * 256);
    const float4* nv4 = (const float4*)(all_e + (size_t)ni * 256);
    float4 uv = uv4[lane];
    float4 pv = pv4[lane];
    float4 nv = nv4[lane];
    float s_up = dot4(uv, pv);
    float s_un = dot4(uv, nv);
    float s_uu = dot4(uv, uv);
    float s_pp = dot4(pv, pv);
    float s_nn = dot4(nv, nv);
#pragma unroll
    for (int off = 32; off >= 1; off >>= 1) {
        s_up += __shfl_xor(s_up, off, 64);
        s_un += __shfl_xor(s_un, off, 64);
        s_uu += __shfl_xor(s_uu, off, 64);
        s_pp += __shfl_xor(s_pp, off, 64);
        s_nn += __shfl_xor(s_nn, off, 64);
    }
    if (lane == 0) {
        float x = s_up - s_un;
        float ls = fminf(x, 0.f) - log1pf(expf(-fabsf(x)));  // log_sigmoid
        partials[wid] = make_float4(-ls, s_uu, s_pp, s_nn);
    }
}

// single-block tree reduction over 4096 float4 partials + final scalar
__global__ __launch_bounds__(256) void reduce_finalize(const float4* __restrict__ partials,
                                                       float* __restrict__ out) {
    __shared__ float4 s[256];
    int t = threadIdx.x;
    float4 a = make_float4(0.f, 0.f, 0.f, 0.f);
    for (int i = t; i < BATCH; i += 256) {
        float4 p = partials[i];
        a.x += p.x; a.y += p.y; a.z += p.z; a.w += p.w;
    }
    s[t] = a;
    __syncthreads();
    for (int off = 128; off >= 1; off >>= 1) {
        if (t < off) {
            s[t].x += s[t + off].x;
            s[t].y += s[t + off].y;
            s[t].z += s[t + off].z;
            s[t].w += s[t + off].w;
        }
        __syncthreads();
    }
    if (t == 0) {
        float bpr = s[0].x / (float)BATCH;
        float l2norm = (s[0].y + s[0].z + sqrtf(s[0].w)) * 0.5f;
        out[0] = bpr + L2_REG_F * l2norm / (float)BATCH;
    }
}

extern "C" void kernel_launch(void* const* d_in, const int* in_sizes, int n_in,
                              void* d_out, int out_size, void* d_ws, size_t ws_size,
                              hipStream_t stream) {
    const int* users = (const int*)d_in[0];
    const int* pos_items = (const int*)d_in[1];
    const int* neg_items = (const int*)d_in[2];
    const int* rows = (const int*)d_in[3];
    const int* cols = (const int*)d_in[4];
    const float* vals = (const float*)d_in[5];
    const float* user_embed = (const float*)d_in[6];
    const float* item_embed = (const float*)d_in[7];
    const float* W1 = (const float*)d_in[8];
    const float* b1 = (const float*)d_in[9];
    const float* W2 = (const float*)d_in[10];
    const float* b2 = (const float*)d_in[11];
    float* out = (float*)d_out;

    char* ws = (char*)d_ws;
    // workspace layout: total ~148 MB
    size_t off_alle = 0;                                     // 102,400,000
    size_t off_packed = off_alle + (size_t)N_CNT * 256 * 4;  // 12,800,000 (4B recs)
    size_t off_Ebf = off_packed + (size_t)NNZ_CNT * 4;       // 12,800,000
    size_t off_Efp8 = off_Ebf + (size_t)N_CNT * D * 2;       // 6,400,000
    size_t off_Lm = off_Efp8 + (size_t)N_CNT * D;            // 12,800,000 (bf16)
    size_t off_rowptr = off_Lm + (size_t)N_CNT * D * 2;      // 400,128
    size_t off_blkB = off_rowptr + 400128;                   // 2,048
    size_t off_bcnt = off_blkB + 2048;                       // 400,384
    size_t off_part = off_bcnt + 400384;                     // 65,536

    float* all_e = (float*)(ws + off_alle);
    float2* bbuf = (float2*)(ws + off_alle);   // aliases all_e; dead before init_E runs
    unsigned int* packed = (unsigned int*)(ws + off_packed);
    unsigned short* Ebf = (unsigned short*)(ws + off_Ebf);
    unsigned char* Efp8 = (unsigned char*)(ws + off_Efp8);
    unsigned short* Lm = (unsigned short*)(ws + off_Lm);
    int* row_ptr = (int*)(ws + off_rowptr);
    int* blkB = (int*)(ws + off_blkB);
    int* bcnt = (int*)(ws + off_bcnt);
    float4* partials = (float4*)(ws + off_part);

    // bucketed multisplit with exclusive per-(bucket,block) regions
    bucket_hist<<<SC_NBLK, 1024, 0, stream>>>(rows, bcnt);
    scan_p1<<<BCNT_NBLK, 256, 0, stream>>>(bcnt, blkB, BCNT_N);
    scan_p2<<<1, 512, 0, stream>>>(blkB, BCNT_NBLK);
    scan_p3<<<BCNT_NBLK, 256, 0, stream>>>(bcnt, blkB, bcnt, BCNT_N);  // in-place
    block_scatter<<<SC_NBLK, 1024, 0, stream>>>(rows, cols, vals, bcnt, bbuf);
    csr_finalize<<<NBUCKET, 1024, 0, stream>>>(bbuf, bcnt, row_ptr, packed);

    // embeddings (after csr_finalize: bbuf aliases all_e)
    init_E<<<(N_CNT * D) / 256, 256, 0, stream>>>(user_embed, item_embed, Ebf, Efp8, all_e);

    for (int l = 0; l < LAYERS; l++) {
        spmm_fp8<<<(N_CNT * 64) / 256, 256, 0, stream>>>(packed, row_ptr, Efp8, Lm);
        layer_fused_mfma<<<784, 256, 0, stream>>>(Lm, Ebf, Efp8,
                                                  W1 + (size_t)l * 4096, b1 + (size_t)l * 64,
                                                  W2 + (size_t)l * 4096, b2 + (size_t)l * 64,
                                                  all_e, l);
    }

    score_kernel<<<(BATCH * 64) / 256, 256, 0, stream>>>(all_e, users, pos_items, neg_items,
                                                         partials);
    reduce_finalize<<<1, 256, 0, stream>>>(partials, out);
}

// Round 9
// 431.793 us; speedup vs baseline: 1.0670x; 1.0408x over previous
//
// NGCF fused pipeline — v7b (depth-3 software-pipelined spmm gather).
// Identical semantics to v7; resubmitted after two broker-side container
// failures (kernel never executed).
#include <hip/hip_runtime.h>
#include <hip/hip_bf16.h>
#include <hip/hip_fp8.h>
#include <math.h>

#define U_CNT 50000
#define I_CNT 50000
#define N_CNT 100000
#define D 64
#define NNZ_CNT 3200000
#define LAYERS 3
#define BATCH 4096
#define L2_REG_F 1e-5f
#define EPS_F 1e-12f

#define NBUCKET 391     // 256 rows per bucket
#define SC_NBLK 256     // scatter blocks (1 per CU), 1024 threads each
#define SC_CHUNK 12500  // NNZ / SC_NBLK
#define BCNT_N (NBUCKET * SC_NBLK)       // 100,096
#define BCNT_NBLK ((BCNT_N + 255) / 256) // 392

typedef __attribute__((ext_vector_type(8))) short short8;
typedef __attribute__((ext_vector_type(4))) float floatx4;
typedef __attribute__((ext_vector_type(2))) float f32x2v;

__device__ __forceinline__ unsigned short f32_to_bf16(float f) {
    unsigned int u = __float_as_uint(f);
    u += 0x7FFFu + ((u >> 16) & 1u);   // round-to-nearest-even
    return (unsigned short)(u >> 16);
}
__device__ __forceinline__ float bf16_to_f32(unsigned short h) {
    return __uint_as_float(((unsigned int)h) << 16);
}
__device__ __forceinline__ float bf16_lo(unsigned int u) {
    return __uint_as_float(u << 16);
}
__device__ __forceinline__ float bf16_hi(unsigned int u) {
    return __uint_as_float(u & 0xFFFF0000u);
}
__device__ __forceinline__ unsigned int pack_bf16(float a, float b) {
    return (unsigned int)f32_to_bf16(a) | ((unsigned int)f32_to_bf16(b) << 16);
}

// ---- fp8 e4m3 (OCP, gfx950). UNSCALED but CLAMPED to +-448: HW cvt does NOT
// saturate; |v|>448 encodes NaN (Round-5 failure). Clamp = 2 VALU per encode.
__device__ __forceinline__ unsigned char f32_to_fp8(float v) {
    v = fminf(fmaxf(v, -448.0f), 448.0f);
#if __has_builtin(__builtin_amdgcn_cvt_pk_fp8_f32)
    return (unsigned char)(__builtin_amdgcn_cvt_pk_fp8_f32(v, 0.0f, 0, false) & 0xFF);
#else
    __hip_fp8_e4m3 t(v);
    return (unsigned char)t.__x;
#endif
}
template <bool HI>
__device__ __forceinline__ f32x2v fp8x2_to_f32(unsigned int w) {
#if __has_builtin(__builtin_amdgcn_cvt_pk_f32_fp8)
    return __builtin_amdgcn_cvt_pk_f32_fp8((int)w, HI);
#else
    unsigned int s = HI ? (w >> 16) : (w & 0xFFFFu);
    __hip_fp8_e4m3 a, b;
    a.__x = (unsigned char)(s & 0xFF);
    b.__x = (unsigned char)((s >> 8) & 0xFF);
    f32x2v r;
    r.x = (float)a;
    r.y = (float)b;
    return r;
#endif
}

// ---------------- init: all_e[:,0:64] fp32; Ebf bf16; Efp8 e4m3 (unscaled)
__global__ void init_E(const float* __restrict__ ue, const float* __restrict__ ie,
                       unsigned short* __restrict__ Ebf, unsigned char* __restrict__ Efp8,
                       float* __restrict__ all_e) {
    int tid = blockIdx.x * blockDim.x + threadIdx.x;
    if (tid >= N_CNT * D) return;
    int row = tid >> 6;
    int d = tid & 63;
    float v = (row < U_CNT) ? ue[tid] : ie[tid - U_CNT * D];
    Ebf[tid] = f32_to_bf16(v);
    Efp8[tid] = f32_to_fp8(v);
    all_e[(size_t)row * 256 + d] = v;
}

// ---------------- generic hierarchical exclusive scan (n <= 512*256)
__global__ void scan_p1(const int* __restrict__ in, int* __restrict__ bsums, int n) {
    __shared__ int s[256];
    int t = threadIdx.x;
    int i = blockIdx.x * 256 + t;
    int v = (i < n) ? in[i] : 0;
    s[t] = v;
    __syncthreads();
    for (int off = 128; off >= 1; off >>= 1) {
        if (t < off) s[t] += s[t + off];
        __syncthreads();
    }
    if (t == 0) bsums[blockIdx.x] = s[0];
}

__global__ void scan_p2(int* __restrict__ bsums, int nblk) {
    __shared__ int s[512];
    int t = threadIdx.x;
    int v = (t < nblk) ? bsums[t] : 0;
    s[t] = v;
    __syncthreads();
    for (int off = 1; off < 512; off <<= 1) {
        int x = (t >= off) ? s[t - off] : 0;
        __syncthreads();
        s[t] += x;
        __syncthreads();
    }
    if (t < nblk) bsums[t] = s[t] - v;  // exclusive
}

__global__ void scan_p3(const int* __restrict__ in, const int* __restrict__ bsums,
                        int* __restrict__ out, int n) {
    __shared__ int s[256];
    int t = threadIdx.x;
    int i = blockIdx.x * 256 + t;
    int v = (i < n) ? in[i] : 0;
    s[t] = v;
    __syncthreads();
    for (int off = 1; off < 256; off <<= 1) {
        int x = (t >= off) ? s[t - off] : 0;
        __syncthreads();
        s[t] += x;
        __syncthreads();
    }
    if (i < n) out[i] = s[t] - v + bsums[blockIdx.x];
}

// ---------------- per-block bucket histogram -> bcnt[bucket*SC_NBLK + blk]
__global__ __launch_bounds__(1024) void bucket_hist(const int* __restrict__ rows,
                                                    int* __restrict__ bcnt) {
    __shared__ int h[NBUCKET];
    int blk = blockIdx.x, t = threadIdx.x;
    if (t < NBUCKET) h[t] = 0;
    __syncthreads();
    int s = blk * SC_CHUNK, e = s + SC_CHUNK;
    for (int i = s + t; i < e; i += 1024) atomicAdd(&h[rows[i] >> 8], 1);
    __syncthreads();
    if (t < NBUCKET) bcnt[t * SC_NBLK + blk] = h[t];
}

// ---------------- scatter into per-(bucket,block) EXCLUSIVE regions (LDS cursors)
__global__ __launch_bounds__(1024) void block_scatter(const int* __restrict__ rows,
                                                      const int* __restrict__ cols,
                                                      const float* __restrict__ vals,
                                                      const int* __restrict__ boff,
                                                      float2* __restrict__ bbuf) {
    __shared__ int cur[NBUCKET];
    int blk = blockIdx.x, t = threadIdx.x;
    if (t < NBUCKET) cur[t] = boff[t * SC_NBLK + blk];
    __syncthreads();
    int s = blk * SC_CHUNK, e = s + SC_CHUNK;
    for (int i = s + t; i < e; i += 1024) {
        int r = rows[i];
        int b = r >> 8;
        int p = atomicAdd(&cur[b], 1);
        unsigned int bits = ((unsigned int)(r & 255) << 17) | (unsigned int)cols[i];
        bbuf[p] = make_float2(vals[i], __uint_as_float(bits));
    }
}

// ---------------- per-bucket: LDS rowlocal hist -> LDS scan -> row_ptr ->
// row-sorted packed (4B records: val_unorm15 << 17 | col17).
__global__ __launch_bounds__(1024) void csr_finalize(const float2* __restrict__ bbuf,
                                                     const int* __restrict__ boff,
                                                     int* __restrict__ row_ptr,
                                                     unsigned int* __restrict__ packed) {
    __shared__ int h[256];
    __shared__ int cur[256];
    int b = blockIdx.x, t = threadIdx.x;
    int s = boff[b * SC_NBLK];
    int e = (b == NBUCKET - 1) ? NNZ_CNT : boff[(b + 1) * SC_NBLK];
    if (t < 256) h[t] = 0;
    __syncthreads();
    for (int i = s + t; i < e; i += 1024)
        atomicAdd(&h[__float_as_uint(bbuf[i].y) >> 17], 1);
    __syncthreads();
    int v = (t < 256) ? h[t] : 0;
    for (int off = 1; off < 256; off <<= 1) {   // Hillis-Steele inclusive scan (t<256)
        int x = (t >= off && t < 256) ? h[t - off] : 0;
        __syncthreads();
        if (t < 256) h[t] += x;
        __syncthreads();
    }
    if (t < 256) {
        int start = s + h[t] - v;  // exclusive + bucket base
        int row = (b << 8) + t;
        if (row < N_CNT) row_ptr[row] = start;
        cur[t] = start;
        if (b == 0 && t == 0) row_ptr[N_CNT] = NNZ_CNT;
    }
    __syncthreads();
    for (int i = s + t; i < e; i += 1024) {
        float2 rec = bbuf[i];
        unsigned int bits = __float_as_uint(rec.y);
        int p = atomicAdd(&cur[bits >> 17], 1);
        unsigned int q = (unsigned int)(rec.x * 32767.0f + 0.5f);  // val in [0,1)
        packed[p] = (q << 17) | (bits & 0x1FFFFu);
    }
}

// ---------------- SpMM: one wave per row; 8 edge slots x 8 lanes.
// Depth-3 software-pipelined gather. Evidence (R0/R4/R6): time invariant to
// bytes/lines/footprint; ~1900 cy per loop iteration == one queued miss
// latency -> the in-order wave stalls at the FMA waitcnt on its SINGLE
// outstanding gather. Pipeline: issue gather[i+16] + packed[i+24] BEFORE
// consuming gather[i] -> 3 gathers + 1 packed in flight per wave.
// Tail slots: u=0 -> vs=0, gathers hot row 0, contributes exactly 0.
__global__ __launch_bounds__(256) void spmm_fp8(const unsigned int* __restrict__ packed,
                                                const int* __restrict__ row_ptr,
                                                const unsigned char* __restrict__ Efp8,
                                                unsigned short* __restrict__ Lm) {
    int wid = (blockIdx.x * blockDim.x + threadIdx.x) >> 6;
    int lane = threadIdx.x & 63;
    if (wid >= N_CNT) return;
    int s = row_ptr[wid];
    int e = row_ptr[wid + 1];
    int eidx = lane >> 3;      // edge slot [0,8)
    int dlane = lane & 7;      // 8 dims each (dlane*8 .. +7)
    int doff = dlane << 3;
    float a0 = 0.f, a1 = 0.f, a2 = 0.f, a3 = 0.f;
    float a4 = 0.f, a5 = 0.f, a6 = 0.f, a7 = 0.f;
    int i = s + eidx;
    unsigned int u0 = (i < e) ? packed[i] : 0u;
    unsigned int u1 = (i + 8 < e) ? packed[i + 8] : 0u;
    unsigned int u2 = (i + 16 < e) ? packed[i + 16] : 0u;
    uint2 g0 = *(const uint2*)(Efp8 + ((size_t)(u0 & 0x1FFFFu) << 6) + doff);
    uint2 g1 = *(const uint2*)(Efp8 + ((size_t)(u1 & 0x1FFFFu) << 6) + doff);
    while (i < e) {
        // issue next gather + next packed record before consuming g0
        uint2 g2 = *(const uint2*)(Efp8 + ((size_t)(u2 & 0x1FFFFu) << 6) + doff);
        int i3 = i + 24;
        unsigned int u3 = (i3 < e) ? packed[i3] : 0u;
        float vs = (float)(u0 >> 17) * (1.0f / 32767.0f);
        f32x2v p0 = fp8x2_to_f32<false>(g0.x);
        f32x2v p1 = fp8x2_to_f32<true>(g0.x);
        f32x2v p2 = fp8x2_to_f32<false>(g0.y);
        f32x2v p3 = fp8x2_to_f32<true>(g0.y);
        a0 += vs * p0.x; a1 += vs * p0.y;
        a2 += vs * p1.x; a3 += vs * p1.y;
        a4 += vs * p2.x; a5 += vs * p2.y;
        a6 += vs * p3.x; a7 += vs * p3.y;
        u0 = u1; u1 = u2; u2 = u3;
        g0 = g1; g1 = g2;
        i += 8;
    }
    // combine the 8 edge slots: lanes with same dlane differ by 8/16/32 in lane id
#pragma unroll
    for (int off = 32; off >= 8; off >>= 1) {
        a0 += __shfl_xor(a0, off, 64); a1 += __shfl_xor(a1, off, 64);
        a2 += __shfl_xor(a2, off, 64); a3 += __shfl_xor(a3, off, 64);
        a4 += __shfl_xor(a4, off, 64); a5 += __shfl_xor(a5, off, 64);
        a6 += __shfl_xor(a6, off, 64); a7 += __shfl_xor(a7, off, 64);
    }
    if (eidx == 0) {  // lanes 0..7 write 16B each -> 128B bf16 row
        unsigned int* dst = (unsigned int*)(Lm + (size_t)wid * D + dlane * 8);
        *(uint4*)dst = make_uint4(pack_bf16(a0, a1), pack_bf16(a2, a3),
                                  pack_bf16(a4, a5), pack_bf16(a6, a7));
    }
}

// ---------------- fused layer via MFMA: Y = leaky([Lm+E | Lm*E] @ [W1;W2] + b1+b2)
// un-normalized Y -> Ebf (bf16) and (layer<2) Efp8 for the next spmm;
// row-normalized Y -> all_e[:, (layer+1)*64:...]
#define AP 136  // A/B^T row stride in shorts (128 + 8 pad -> 4-bank stagger)
__global__ __launch_bounds__(256) void layer_fused_mfma(const unsigned short* __restrict__ Lm,
                                                        unsigned short* __restrict__ Ebf,
                                                        unsigned char* __restrict__ Efp8,
                                                        const float* __restrict__ W1,
                                                        const float* __restrict__ b1,
                                                        const float* __restrict__ W2,
                                                        const float* __restrict__ b2,
                                                        float* __restrict__ all_e, int layer) {
    __shared__ unsigned short sBt[64 * AP];    // B^T[n][k] bf16 (k<64: W1, k>=64: W2)
    __shared__ float sBias[64];
    __shared__ unsigned short sA[4][16 * AP];  // per-wave A staging (also fp8 out staging)

    int t = threadIdx.x;
    for (int i = t; i < 4096; i += 256) {
        int k = i >> 6, n = i & 63;
        sBt[n * AP + k] = f32_to_bf16(W1[i]);
        sBt[n * AP + 64 + k] = f32_to_bf16(W2[i]);
    }
    if (t < 64) sBias[t] = b1[t] + b2[t];
    __syncthreads();

    int w = t >> 6, lane = t & 63;
    int quad = lane >> 4, l16 = lane & 15;

    short8 bfrag[4][4];
#pragma unroll
    for (int ks = 0; ks < 4; ks++)
#pragma unroll
        for (int ct = 0; ct < 4; ct++)
            bfrag[ks][ct] = *(const short8*)&sBt[(ct * 16 + l16) * AP + ks * 32 + quad * 8];

    float bias[4];
#pragma unroll
    for (int ct = 0; ct < 4; ct++) bias[ct] = sBias[ct * 16 + l16];

    unsigned short* A = sA[w];
    int col_off = (layer + 1) * 64;
    int nwaves = gridDim.x * 4;

    for (int tile = blockIdx.x * 4 + w; tile < N_CNT / 16; tile += nwaves) {
        int rbase = tile * 16;
#pragma unroll
        for (int p = 0; p < 4; p++) {
            int r = p * 4 + quad;
            int c = l16 * 4;
            uint2 lw = *(const uint2*)(Lm + (size_t)(rbase + r) * 64 + c);
            float l0 = bf16_lo(lw.x), l1 = bf16_hi(lw.x);
            float l2 = bf16_lo(lw.y), l3 = bf16_hi(lw.y);
            ushort4 eh = *(const ushort4*)(Ebf + (size_t)(rbase + r) * 64 + c);
            float e0 = bf16_to_f32(eh.x), e1 = bf16_to_f32(eh.y);
            float e2 = bf16_to_f32(eh.z), e3 = bf16_to_f32(eh.w);
            *(uint2*)&A[r * AP + c] = make_uint2(pack_bf16(l0 + e0, l1 + e1),
                                                pack_bf16(l2 + e2, l3 + e3));
            *(uint2*)&A[r * AP + 64 + c] = make_uint2(pack_bf16(l0 * e0, l1 * e1),
                                                      pack_bf16(l2 * e2, l3 * e3));
        }
        floatx4 acc[4];
#pragma unroll
        for (int ct = 0; ct < 4; ct++) {
            acc[ct][0] = bias[ct]; acc[ct][1] = bias[ct];
            acc[ct][2] = bias[ct]; acc[ct][3] = bias[ct];
        }
#pragma unroll
        for (int ks = 0; ks < 4; ks++) {
            short8 af = *(const short8*)&A[l16 * AP + ks * 32 + quad * 8];
#pragma unroll
            for (int ct = 0; ct < 4; ct++)
                acc[ct] = __builtin_amdgcn_mfma_f32_16x16x32_bf16(af, bfrag[ks][ct], acc[ct], 0, 0, 0);
        }
        float y[4][4];
        float ssq[4] = {0.f, 0.f, 0.f, 0.f};
#pragma unroll
        for (int ct = 0; ct < 4; ct++)
#pragma unroll
            for (int reg = 0; reg < 4; reg++) {
                float v = acc[ct][reg];
                v = (v > 0.f) ? v : 0.2f * v;
                y[ct][reg] = v;
                ssq[reg] += v * v;
            }
#pragma unroll
        for (int reg = 0; reg < 4; reg++) {
            float ss = ssq[reg];
            ss += __shfl_xor(ss, 1, 64);
            ss += __shfl_xor(ss, 2, 64);
            ss += __shfl_xor(ss, 4, 64);
            ss += __shfl_xor(ss, 8, 64);
            ssq[reg] = fmaxf(sqrtf(ss), EPS_F);
        }
#pragma unroll
        for (int reg = 0; reg < 4; reg++) {
            int row = rbase + quad * 4 + reg;
            float inv = 1.0f / ssq[reg];
#pragma unroll
            for (int ct = 0; ct < 4; ct++) {
                int col = ct * 16 + l16;
                float v = y[ct][reg];
                Ebf[(size_t)row * 64 + col] = f32_to_bf16(v);
                all_e[(size_t)row * 256 + col_off + col] = v * inv;
            }
        }
        if (layer < 2) {
            // fp8 copy for the next spmm's gathers, staged via per-wave LDS
            unsigned char* sb = (unsigned char*)A;  // A already consumed
#pragma unroll
            for (int reg = 0; reg < 4; reg++) {
                int rl = quad * 4 + reg;
#pragma unroll
                for (int ct = 0; ct < 4; ct++)
                    sb[rl * 64 + ct * 16 + l16] = f32_to_fp8(y[ct][reg]);
            }
            __builtin_amdgcn_wave_barrier();
            uint4 ov = *(const uint4*)(sb + lane * 16);   // 16 rows x 64B = 1KB/wave
            *(uint4*)(Efp8 + (size_t)rbase * 64 + lane * 16) = ov;
        }
    }
}

// ---------------- scoring: one wave per sample, per-sample partials (NO atomics)
__device__ __forceinline__ float dot4(float4 a, float4 b) {
    return a.x * b.x + a.y * b.y + a.z * b.z + a.w * b.w;
}

__global__ __launch_bounds__(256) void score_kernel(const float* __restrict__ all_e,
                                                    const int* __restrict__ users,
                                                    const int* __restrict__ pos,
                                                    const int* __restrict__ neg,
                                                    float4* __restrict__ partials) {
    int wid = (blockIdx.x * blockDim.x + threadIdx.x) >> 6;
    int lane = threadIdx.x & 63;
    if (wid >= BATCH) return;
    int ui = users[wid];
    int pi = pos[wid];
    int ni = neg[wid];
    const float4* uv4 = (const float4*)(all_e + (size_t)ui * 256);
    const float4* pv4 = (const float4*)(all_e + (size_t)pi * 256);
    const float4* nv4 = (const float4*)(all_e + (size_t)ni * 256);
    float4 uv = uv4[lane];
    float4 pv = pv4[lane];
    float4 nv = nv4[lane];
    float s_up = dot4(uv, pv);
    float s_un = dot4(uv, nv);
    float s_uu = dot4(uv, uv);
    float s_pp = dot4(pv, pv);
    float s_nn = dot4(nv, nv);
#pragma unroll
    for (int off = 32; off >= 1; off >>= 1) {
        s_up += __shfl_xor(s_up, off, 64);
        s_un += __shfl_xor(s_un, off, 64);
        s_uu += __shfl_xor(s_uu, off, 64);
        s_pp += __shfl_xor(s_pp, off, 64);
        s_nn += __shfl_xor(s_nn, off, 64);
    }
    if (lane == 0) {
        float x = s_up - s_un;
        float ls = fminf(x, 0.f) - log1pf(expf(-fabsf(x)));  // log_sigmoid
        partials[wid] = make_float4(-ls, s_uu, s_pp, s_nn);
    }
}

// single-block tree reduction over 4096 float4 partials + final scalar
__global__ __launch_bounds__(256) void reduce_finalize(const float4* __restrict__ partials,
                                                       float* __restrict__ out) {
    __shared__ float4 s[256];
    int t = threadIdx.x;
    float4 a = make_float4(0.f, 0.f, 0.f, 0.f);
    for (int i = t; i < BATCH; i += 256) {
        float4 p = partials[i];
        a.x += p.x; a.y += p.y; a.z += p.z; a.w += p.w;
    }
    s[t] = a;
    __syncthreads();
    for (int off = 128; off >= 1; off >>= 1) {
        if (t < off) {
            s[t].x += s[t + off].x;
            s[t].y += s[t + off].y;
            s[t].z += s[t + off].z;
            s[t].w += s[t + off].w;
        }
        __syncthreads();
    }
    if (t == 0) {
        float bpr = s[0].x / (float)BATCH;
        float l2norm = (s[0].y + s[0].z + sqrtf(s[0].w)) * 0.5f;
        out[0] = bpr + L2_REG_F * l2norm / (float)BATCH;
    }
}

extern "C" void kernel_launch(void* const* d_in, const int* in_sizes, int n_in,
                              void* d_out, int out_size, void* d_ws, size_t ws_size,
                              hipStream_t stream) {
    const int* users = (const int*)d_in[0];
    const int* pos_items = (const int*)d_in[1];
    const int* neg_items = (const int*)d_in[2];
    const int* rows = (const int*)d_in[3];
    const int* cols = (const int*)d_in[4];
    const float* vals = (const float*)d_in[5];
    const float* user_embed = (const float*)d_in[6];
    const float* item_embed = (const float*)d_in[7];
    const float* W1 = (const float*)d_in[8];
    const float* b1 = (const float*)d_in[9];
    const float* W2 = (const float*)d_in[10];
    const float* b2 = (const float*)d_in[11];
    float* out = (float*)d_out;

    char* ws = (char*)d_ws;
    // workspace layout: total ~148 MB
    size_t off_alle = 0;                                     // 102,400,000
    size_t off_packed = off_alle + (size_t)N_CNT * 256 * 4;  // 12,800,000 (4B recs)
    size_t off_Ebf = off_packed + (size_t)NNZ_CNT * 4;       // 12,800,000
    size_t off_Efp8 = off_Ebf + (size_t)N_CNT * D * 2;       // 6,400,000
    size_t off_Lm = off_Efp8 + (size_t)N_CNT * D;            // 12,800,000 (bf16)
    size_t off_rowptr = off_Lm + (size_t)N_CNT * D * 2;      // 400,128
    size_t off_blkB = off_rowptr + 400128;                   // 2,048
    size_t off_bcnt = off_blkB + 2048;                       // 400,384
    size_t off_part = off_bcnt + 400384;                     // 65,536

    float* all_e = (float*)(ws + off_alle);
    float2* bbuf = (float2*)(ws + off_alle);   // aliases all_e; dead before init_E runs
    unsigned int* packed = (unsigned int*)(ws + off_packed);
    unsigned short* Ebf = (unsigned short*)(ws + off_Ebf);
    unsigned char* Efp8 = (unsigned char*)(ws + off_Efp8);
    unsigned short* Lm = (unsigned short*)(ws + off_Lm);
    int* row_ptr = (int*)(ws + off_rowptr);
    int* blkB = (int*)(ws + off_blkB);
    int* bcnt = (int*)(ws + off_bcnt);
    float4* partials = (float4*)(ws + off_part);

    // bucketed multisplit with exclusive per-(bucket,block) regions
    bucket_hist<<<SC_NBLK, 1024, 0, stream>>>(rows, bcnt);
    scan_p1<<<BCNT_NBLK, 256, 0, stream>>>(bcnt, blkB, BCNT_N);
    scan_p2<<<1, 512, 0, stream>>>(blkB, BCNT_NBLK);
    scan_p3<<<BCNT_NBLK, 256, 0, stream>>>(bcnt, blkB, bcnt, BCNT_N);  // in-place
    block_scatter<<<SC_NBLK, 1024, 0, stream>>>(rows, cols, vals, bcnt, bbuf);
    csr_finalize<<<NBUCKET, 1024, 0, stream>>>(bbuf, bcnt, row_ptr, packed);

    // embeddings (after csr_finalize: bbuf aliases all_e)
    init_E<<<(N_CNT * D) / 256, 256, 0, stream>>>(user_embed, item_embed, Ebf, Efp8, all_e);

    for (int l = 0; l < LAYERS; l++) {
        spmm_fp8<<<(N_CNT * 64) / 256, 256, 0, stream>>>(packed, row_ptr, Efp8, Lm);
        layer_fused_mfma<<<784, 256, 0, stream>>>(Lm, Ebf, Efp8,
                                                  W1 + (size_t)l * 4096, b1 + (size_t)l * 64,
                                                  W2 + (size_t)l * 4096, b2 + (size_t)l * 64,
                                                  all_e, l);
    }

    score_kernel<<<(BATCH * 64) / 256, 256, 0, stream>>>(all_e, users, pos_items, neg_items,
                                                         partials);
    reduce_finalize<<<1, 256, 0, stream>>>(partials, out);
}

// Round 10
// 417.064 us; speedup vs baseline: 1.1047x; 1.0353x over previous
//
// NGCF fused pipeline — v8: spmm VALU trim (packed FMA + folded val decode +
// uniform trip count). R9 result: depth-3 pipeline 60.5->54.5us, VALUBusy 70%
// -> now VALU-issue-bound; this round cuts instructions per iteration.
#include <hip/hip_runtime.h>
#include <hip/hip_bf16.h>
#include <hip/hip_fp8.h>
#include <math.h>

#define U_CNT 50000
#define I_CNT 50000
#define N_CNT 100000
#define D 64
#define NNZ_CNT 3200000
#define LAYERS 3
#define BATCH 4096
#define L2_REG_F 1e-5f
#define EPS_F 1e-12f

#define NBUCKET 391     // 256 rows per bucket
#define SC_NBLK 256     // scatter blocks (1 per CU), 1024 threads each
#define SC_CHUNK 12500  // NNZ / SC_NBLK
#define BCNT_N (NBUCKET * SC_NBLK)       // 100,096
#define BCNT_NBLK ((BCNT_N + 255) / 256) // 392

typedef __attribute__((ext_vector_type(8))) short short8;
typedef __attribute__((ext_vector_type(4))) float floatx4;
typedef __attribute__((ext_vector_type(2))) float f32x2v;

__device__ __forceinline__ unsigned short f32_to_bf16(float f) {
    unsigned int u = __float_as_uint(f);
    u += 0x7FFFu + ((u >> 16) & 1u);   // round-to-nearest-even
    return (unsigned short)(u >> 16);
}
__device__ __forceinline__ float bf16_to_f32(unsigned short h) {
    return __uint_as_float(((unsigned int)h) << 16);
}
__device__ __forceinline__ float bf16_lo(unsigned int u) {
    return __uint_as_float(u << 16);
}
__device__ __forceinline__ float bf16_hi(unsigned int u) {
    return __uint_as_float(u & 0xFFFF0000u);
}
__device__ __forceinline__ unsigned int pack_bf16(float a, float b) {
    return (unsigned int)f32_to_bf16(a) | ((unsigned int)f32_to_bf16(b) << 16);
}

// ---- fp8 e4m3 (OCP, gfx950). UNSCALED but CLAMPED to +-448: HW cvt does NOT
// saturate; |v|>448 encodes NaN (Round-5 failure). Clamp = 2 VALU per encode.
__device__ __forceinline__ unsigned char f32_to_fp8(float v) {
    v = fminf(fmaxf(v, -448.0f), 448.0f);
#if __has_builtin(__builtin_amdgcn_cvt_pk_fp8_f32)
    return (unsigned char)(__builtin_amdgcn_cvt_pk_fp8_f32(v, 0.0f, 0, false) & 0xFF);
#else
    __hip_fp8_e4m3 t(v);
    return (unsigned char)t.__x;
#endif
}
template <bool HI>
__device__ __forceinline__ f32x2v fp8x2_to_f32(unsigned int w) {
#if __has_builtin(__builtin_amdgcn_cvt_pk_f32_fp8)
    return __builtin_amdgcn_cvt_pk_f32_fp8((int)w, HI);
#else
    unsigned int s = HI ? (w >> 16) : (w & 0xFFFFu);
    __hip_fp8_e4m3 a, b;
    a.__x = (unsigned char)(s & 0xFF);
    b.__x = (unsigned char)((s >> 8) & 0xFF);
    f32x2v r;
    r.x = (float)a;
    r.y = (float)b;
    return r;
#endif
}

// ---------------- init: all_e[:,0:64] fp32; Ebf bf16; Efp8 e4m3 (unscaled)
__global__ void init_E(const float* __restrict__ ue, const float* __restrict__ ie,
                       unsigned short* __restrict__ Ebf, unsigned char* __restrict__ Efp8,
                       float* __restrict__ all_e) {
    int tid = blockIdx.x * blockDim.x + threadIdx.x;
    if (tid >= N_CNT * D) return;
    int row = tid >> 6;
    int d = tid & 63;
    float v = (row < U_CNT) ? ue[tid] : ie[tid - U_CNT * D];
    Ebf[tid] = f32_to_bf16(v);
    Efp8[tid] = f32_to_fp8(v);
    all_e[(size_t)row * 256 + d] = v;
}

// ---------------- generic hierarchical exclusive scan (n <= 512*256)
__global__ void scan_p1(const int* __restrict__ in, int* __restrict__ bsums, int n) {
    __shared__ int s[256];
    int t = threadIdx.x;
    int i = blockIdx.x * 256 + t;
    int v = (i < n) ? in[i] : 0;
    s[t] = v;
    __syncthreads();
    for (int off = 128; off >= 1; off >>= 1) {
        if (t < off) s[t] += s[t + off];
        __syncthreads();
    }
    if (t == 0) bsums[blockIdx.x] = s[0];
}

__global__ void scan_p2(int* __restrict__ bsums, int nblk) {
    __shared__ int s[512];
    int t = threadIdx.x;
    int v = (t < nblk) ? bsums[t] : 0;
    s[t] = v;
    __syncthreads();
    for (int off = 1; off < 512; off <<= 1) {
        int x = (t >= off) ? s[t - off] : 0;
        __syncthreads();
        s[t] += x;
        __syncthreads();
    }
    if (t < nblk) bsums[t] = s[t] - v;  // exclusive
}

__global__ void scan_p3(const int* __restrict__ in, const int* __restrict__ bsums,
                        int* __restrict__ out, int n) {
    __shared__ int s[256];
    int t = threadIdx.x;
    int i = blockIdx.x * 256 + t;
    int v = (i < n) ? in[i] : 0;
    s[t] = v;
    __syncthreads();
    for (int off = 1; off < 256; off <<= 1) {
        int x = (t >= off) ? s[t - off] : 0;
        __syncthreads();
        s[t] += x;
        __syncthreads();
    }
    if (i < n) out[i] = s[t] - v + bsums[blockIdx.x];
}

// ---------------- per-block bucket histogram -> bcnt[bucket*SC_NBLK + blk]
__global__ __launch_bounds__(1024) void bucket_hist(const int* __restrict__ rows,
                                                    int* __restrict__ bcnt) {
    __shared__ int h[NBUCKET];
    int blk = blockIdx.x, t = threadIdx.x;
    if (t < NBUCKET) h[t] = 0;
    __syncthreads();
    int s = blk * SC_CHUNK, e = s + SC_CHUNK;
    for (int i = s + t; i < e; i += 1024) atomicAdd(&h[rows[i] >> 8], 1);
    __syncthreads();
    if (t < NBUCKET) bcnt[t * SC_NBLK + blk] = h[t];
}

// ---------------- scatter into per-(bucket,block) EXCLUSIVE regions (LDS cursors)
__global__ __launch_bounds__(1024) void block_scatter(const int* __restrict__ rows,
                                                      const int* __restrict__ cols,
                                                      const float* __restrict__ vals,
                                                      const int* __restrict__ boff,
                                                      float2* __restrict__ bbuf) {
    __shared__ int cur[NBUCKET];
    int blk = blockIdx.x, t = threadIdx.x;
    if (t < NBUCKET) cur[t] = boff[t * SC_NBLK + blk];
    __syncthreads();
    int s = blk * SC_CHUNK, e = s + SC_CHUNK;
    for (int i = s + t; i < e; i += 1024) {
        int r = rows[i];
        int b = r >> 8;
        int p = atomicAdd(&cur[b], 1);
        unsigned int bits = ((unsigned int)(r & 255) << 17) | (unsigned int)cols[i];
        bbuf[p] = make_float2(vals[i], __uint_as_float(bits));
    }
}

// ---------------- per-bucket: LDS rowlocal hist -> LDS scan -> row_ptr ->
// row-sorted packed (4B records: val_unorm15 << 17 | col17).
__global__ __launch_bounds__(1024) void csr_finalize(const float2* __restrict__ bbuf,
                                                     const int* __restrict__ boff,
                                                     int* __restrict__ row_ptr,
                                                     unsigned int* __restrict__ packed) {
    __shared__ int h[256];
    __shared__ int cur[256];
    int b = blockIdx.x, t = threadIdx.x;
    int s = boff[b * SC_NBLK];
    int e = (b == NBUCKET - 1) ? NNZ_CNT : boff[(b + 1) * SC_NBLK];
    if (t < 256) h[t] = 0;
    __syncthreads();
    for (int i = s + t; i < e; i += 1024)
        atomicAdd(&h[__float_as_uint(bbuf[i].y) >> 17], 1);
    __syncthreads();
    int v = (t < 256) ? h[t] : 0;
    for (int off = 1; off < 256; off <<= 1) {   // Hillis-Steele inclusive scan (t<256)
        int x = (t >= off && t < 256) ? h[t - off] : 0;
        __syncthreads();
        if (t < 256) h[t] += x;
        __syncthreads();
    }
    if (t < 256) {
        int start = s + h[t] - v;  // exclusive + bucket base
        int row = (b << 8) + t;
        if (row < N_CNT) row_ptr[row] = start;
        cur[t] = start;
        if (b == 0 && t == 0) row_ptr[N_CNT] = NNZ_CNT;
    }
    __syncthreads();
    for (int i = s + t; i < e; i += 1024) {
        float2 rec = bbuf[i];
        unsigned int bits = __float_as_uint(rec.y);
        int p = atomicAdd(&cur[bits >> 17], 1);
        unsigned int q = (unsigned int)(rec.x * 32767.0f + 0.5f);  // val in [0,1)
        packed[p] = (q << 17) | (bits & 0x1FFFFu);
    }
}

// ---------------- SpMM: one wave per row; 8 edge slots x 8 lanes.
// v8: depth-3 pipeline (R9: 60.5->54.5us) + VALU trims:
//  - f32x2 packed accumulate -> v_pk_fma_f32 (8 FMA insts -> 4)
//  - vs = (float)u * 1/(32767*131072): col bits add <=3.05e-5 abs error on a
//    [0,1) val (negligible vs fp8's 2%) and kill the shift
//  - wave-uniform trip count (s,e uniform; dummy slots contribute exactly 0)
//    -> countable loop, unrollable, rotation movs renamed away
__global__ __launch_bounds__(256) void spmm_fp8(const unsigned int* __restrict__ packed,
                                                const int* __restrict__ row_ptr,
                                                const unsigned char* __restrict__ Efp8,
                                                unsigned short* __restrict__ Lm) {
    int wid = (blockIdx.x * blockDim.x + threadIdx.x) >> 6;
    int lane = threadIdx.x & 63;
    if (wid >= N_CNT) return;
    int s = row_ptr[wid];
    int e = row_ptr[wid + 1];
    int eidx = lane >> 3;      // edge slot [0,8)
    int dlane = lane & 7;      // 8 dims each (dlane*8 .. +7)
    const unsigned char* Eb = Efp8 + (dlane << 3);
    const float VK = 1.0f / (32767.0f * 131072.0f);
    f32x2v a01 = {0.f, 0.f}, a23 = {0.f, 0.f}, a45 = {0.f, 0.f}, a67 = {0.f, 0.f};
    int nit = (e - s + 7) >> 3;   // wave-uniform iteration count
    int i = s + eidx;
    unsigned int u0 = (i < e) ? packed[i] : 0u;
    unsigned int u1 = (i + 8 < e) ? packed[i + 8] : 0u;
    unsigned int u2 = (i + 16 < e) ? packed[i + 16] : 0u;
    uint2 g0 = *(const uint2*)(Eb + ((size_t)(u0 & 0x1FFFFu) << 6));
    uint2 g1 = *(const uint2*)(Eb + ((size_t)(u1 & 0x1FFFFu) << 6));
#pragma unroll 2
    for (int it = 0; it < nit; ++it) {
        // issue next gather + next packed record before consuming g0
        uint2 g2 = *(const uint2*)(Eb + ((size_t)(u2 & 0x1FFFFu) << 6));
        int i3 = i + 24;
        unsigned int u3 = (i3 < e) ? packed[i3] : 0u;
        float vs = (float)u0 * VK;   // includes col-bit error <= 3.05e-5 abs
        f32x2v vv = {vs, vs};
        a01 += vv * fp8x2_to_f32<false>(g0.x);
        a23 += vv * fp8x2_to_f32<true>(g0.x);
        a45 += vv * fp8x2_to_f32<false>(g0.y);
        a67 += vv * fp8x2_to_f32<true>(g0.y);
        u0 = u1; u1 = u2; u2 = u3;
        g0 = g1; g1 = g2;
        i += 8;
    }
    float a0 = a01.x, a1 = a01.y, a2 = a23.x, a3 = a23.y;
    float a4 = a45.x, a5 = a45.y, a6 = a67.x, a7 = a67.y;
    // combine the 8 edge slots: lanes with same dlane differ by 8/16/32 in lane id
#pragma unroll
    for (int off = 32; off >= 8; off >>= 1) {
        a0 += __shfl_xor(a0, off, 64); a1 += __shfl_xor(a1, off, 64);
        a2 += __shfl_xor(a2, off, 64); a3 += __shfl_xor(a3, off, 64);
        a4 += __shfl_xor(a4, off, 64); a5 += __shfl_xor(a5, off, 64);
        a6 += __shfl_xor(a6, off, 64); a7 += __shfl_xor(a7, off, 64);
    }
    if (eidx == 0) {  // lanes 0..7 write 16B each -> 128B bf16 row
        unsigned int* dst = (unsigned int*)(Lm + (size_t)wid * D + dlane * 8);
        *(uint4*)dst = make_uint4(pack_bf16(a0, a1), pack_bf16(a2, a3),
                                  pack_bf16(a4, a5), pack_bf16(a6, a7));
    }
}

// ---------------- fused layer via MFMA: Y = leaky([Lm+E | Lm*E] @ [W1;W2] + b1+b2)
// un-normalized Y -> Ebf (bf16) and (layer<2) Efp8 for the next spmm;
// row-normalized Y -> all_e[:, (layer+1)*64:...]
#define AP 136  // A/B^T row stride in shorts (128 + 8 pad -> 4-bank stagger)
__global__ __launch_bounds__(256) void layer_fused_mfma(const unsigned short* __restrict__ Lm,
                                                        unsigned short* __restrict__ Ebf,
                                                        unsigned char* __restrict__ Efp8,
                                                        const float* __restrict__ W1,
                                                        const float* __restrict__ b1,
                                                        const float* __restrict__ W2,
                                                        const float* __restrict__ b2,
                                                        float* __restrict__ all_e, int layer) {
    __shared__ unsigned short sBt[64 * AP];    // B^T[n][k] bf16 (k<64: W1, k>=64: W2)
    __shared__ float sBias[64];
    __shared__ unsigned short sA[4][16 * AP];  // per-wave A staging (also fp8 out staging)

    int t = threadIdx.x;
    for (int i = t; i < 4096; i += 256) {
        int k = i >> 6, n = i & 63;
        sBt[n * AP + k] = f32_to_bf16(W1[i]);
        sBt[n * AP + 64 + k] = f32_to_bf16(W2[i]);
    }
    if (t < 64) sBias[t] = b1[t] + b2[t];
    __syncthreads();

    int w = t >> 6, lane = t & 63;
    int quad = lane >> 4, l16 = lane & 15;

    short8 bfrag[4][4];
#pragma unroll
    for (int ks = 0; ks < 4; ks++)
#pragma unroll
        for (int ct = 0; ct < 4; ct++)
            bfrag[ks][ct] = *(const short8*)&sBt[(ct * 16 + l16) * AP + ks * 32 + quad * 8];

    float bias[4];
#pragma unroll
    for (int ct = 0; ct < 4; ct++) bias[ct] = sBias[ct * 16 + l16];

    unsigned short* A = sA[w];
    int col_off = (layer + 1) * 64;
    int nwaves = gridDim.x * 4;

    for (int tile = blockIdx.x * 4 + w; tile < N_CNT / 16; tile += nwaves) {
        int rbase = tile * 16;
#pragma unroll
        for (int p = 0; p < 4; p++) {
            int r = p * 4 + quad;
            int c = l16 * 4;
            uint2 lw = *(const uint2*)(Lm + (size_t)(rbase + r) * 64 + c);
            float l0 = bf16_lo(lw.x), l1 = bf16_hi(lw.x);
            float l2 = bf16_lo(lw.y), l3 = bf16_hi(lw.y);
            ushort4 eh = *(const ushort4*)(Ebf + (size_t)(rbase + r) * 64 + c);
            float e0 = bf16_to_f32(eh.x), e1 = bf16_to_f32(eh.y);
            float e2 = bf16_to_f32(eh.z), e3 = bf16_to_f32(eh.w);
            *(uint2*)&A[r * AP + c] = make_uint2(pack_bf16(l0 + e0, l1 + e1),
                                                pack_bf16(l2 + e2, l3 + e3));
            *(uint2*)&A[r * AP + 64 + c] = make_uint2(pack_bf16(l0 * e0, l1 * e1),
                                                      pack_bf16(l2 * e2, l3 * e3));
        }
        floatx4 acc[4];
#pragma unroll
        for (int ct = 0; ct < 4; ct++) {
            acc[ct][0] = bias[ct]; acc[ct][1] = bias[ct];
            acc[ct][2] = bias[ct]; acc[ct][3] = bias[ct];
        }
#pragma unroll
        for (int ks = 0; ks < 4; ks++) {
            short8 af = *(const short8*)&A[l16 * AP + ks * 32 + quad * 8];
#pragma unroll
            for (int ct = 0; ct < 4; ct++)
                acc[ct] = __builtin_amdgcn_mfma_f32_16x16x32_bf16(af, bfrag[ks][ct], acc[ct], 0, 0, 0);
        }
        float y[4][4];
        float ssq[4] = {0.f, 0.f, 0.f, 0.f};
#pragma unroll
        for (int ct = 0; ct < 4; ct++)
#pragma unroll
            for (int reg = 0; reg < 4; reg++) {
                float v = acc[ct][reg];
                v = (v > 0.f) ? v : 0.2f * v;
                y[ct][reg] = v;
                ssq[reg] += v * v;
            }
#pragma unroll
        for (int reg = 0; reg < 4; reg++) {
            float ss = ssq[reg];
            ss += __shfl_xor(ss, 1, 64);
            ss += __shfl_xor(ss, 2, 64);
            ss += __shfl_xor(ss, 4, 64);
            ss += __shfl_xor(ss, 8, 64);
            ssq[reg] = fmaxf(sqrtf(ss), EPS_F);
        }
#pragma unroll
        for (int reg = 0; reg < 4; reg++) {
            int row = rbase + quad * 4 + reg;
            float inv = 1.0f / ssq[reg];
#pragma unroll
            for (int ct = 0; ct < 4; ct++) {
                int col = ct * 16 + l16;
                float v = y[ct][reg];
                Ebf[(size_t)row * 64 + col] = f32_to_bf16(v);
                all_e[(size_t)row * 256 + col_off + col] = v * inv;
            }
        }
        if (layer < 2) {
            // fp8 copy for the next spmm's gathers, staged via per-wave LDS
            unsigned char* sb = (unsigned char*)A;  // A already consumed
#pragma unroll
            for (int reg = 0; reg < 4; reg++) {
                int rl = quad * 4 + reg;
#pragma unroll
                for (int ct = 0; ct < 4; ct++)
                    sb[rl * 64 + ct * 16 + l16] = f32_to_fp8(y[ct][reg]);
            }
            __builtin_amdgcn_wave_barrier();
            uint4 ov = *(const uint4*)(sb + lane * 16);   // 16 rows x 64B = 1KB/wave
            *(uint4*)(Efp8 + (size_t)rbase * 64 + lane * 16) = ov;
        }
    }
}

// ---------------- scoring: one wave per sample, per-sample partials (NO atomics)
__device__ __forceinline__ float dot4(float4 a, float4 b) {
    return a.x * b.x + a.y * b.y + a.z * b.z + a.w * b.w;
}

__global__ __launch_bounds__(256) void score_kernel(const float* __restrict__ all_e,
                                                    const int* __restrict__ users,
                                                    const int* __restrict__ pos,
                                                    const int* __restrict__ neg,
                                                    float4* __restrict__ partials) {
    int wid = (blockIdx.x * blockDim.x + threadIdx.x) >> 6;
    int lane = threadIdx.x & 63;
    if (wid >= BATCH) return;
    int ui = users[wid];
    int pi = pos[wid];
    int ni = neg[wid];
    const float4* uv4 = (const float4*)(all_e + (size_t)ui * 256);
    const float4* pv4 = (const float4*)(all_e + (size_t)pi * 256);
    const float4* nv4 = (const float4*)(all_e + (size_t)ni * 256);
    float4 uv = uv4[lane];
    float4 pv = pv4[lane];
    float4 nv = nv4[lane];
    float s_up = dot4(uv, pv);
    float s_un = dot4(uv, nv);
    float s_uu = dot4(uv, uv);
    float s_pp = dot4(pv, pv);
    float s_nn = dot4(nv, nv);
#pragma unroll
    for (int off = 32; off >= 1; off >>= 1) {
        s_up += __shfl_xor(s_up, off, 64);
        s_un += __shfl_xor(s_un, off, 64);
        s_uu += __shfl_xor(s_uu, off, 64);
        s_pp += __shfl_xor(s_pp, off, 64);
        s_nn += __shfl_xor(s_nn, off, 64);
    }
    if (lane == 0) {
        float x = s_up - s_un;
        float ls = fminf(x, 0.f) - log1pf(expf(-fabsf(x)));  // log_sigmoid
        partials[wid] = make_float4(-ls, s_uu, s_pp, s_nn);
    }
}

// single-block tree reduction over 4096 float4 partials + final scalar
__global__ __launch_bounds__(256) void reduce_finalize(const float4* __restrict__ partials,
                                                       float* __restrict__ out) {
    __shared__ float4 s[256];
    int t = threadIdx.x;
    float4 a = make_float4(0.f, 0.f, 0.f, 0.f);
    for (int i = t; i < BATCH; i += 256) {
        float4 p = partials[i];
        a.x += p.x; a.y += p.y; a.z += p.z; a.w += p.w;
    }
    s[t] = a;
    __syncthreads();
    for (int off = 128; off >= 1; off >>= 1) {
        if (t < off) {
            s[t].x += s[t + off].x;
            s[t].y += s[t + off].y;
            s[t].z += s[t + off].z;
            s[t].w += s[t + off].w;
        }
        __syncthreads();
    }
    if (t == 0) {
        float bpr = s[0].x / (float)BATCH;
        float l2norm = (s[0].y + s[0].z + sqrtf(s[0].w)) * 0.5f;
        out[0] = bpr + L2_REG_F * l2norm / (float)BATCH;
    }
}

extern "C" void kernel_launch(void* const* d_in, const int* in_sizes, int n_in,
                              void* d_out, int out_size, void* d_ws, size_t ws_size,
                              hipStream_t stream) {
    const int* users = (const int*)d_in[0];
    const int* pos_items = (const int*)d_in[1];
    const int* neg_items = (const int*)d_in[2];
    const int* rows = (const int*)d_in[3];
    const int* cols = (const int*)d_in[4];
    const float* vals = (const float*)d_in[5];
    const float* user_embed = (const float*)d_in[6];
    const float* item_embed = (const float*)d_in[7];
    const float* W1 = (const float*)d_in[8];
    const float* b1 = (const float*)d_in[9];
    const float* W2 = (const float*)d_in[10];
    const float* b2 = (const float*)d_in[11];
    float* out = (float*)d_out;

    char* ws = (char*)d_ws;
    // workspace layout: total ~148 MB
    size_t off_alle = 0;                                     // 102,400,000
    size_t off_packed = off_alle + (size_t)N_CNT * 256 * 4;  // 12,800,000 (4B recs)
    size_t off_Ebf = off_packed + (size_t)NNZ_CNT * 4;       // 12,800,000
    size_t off_Efp8 = off_Ebf + (size_t)N_CNT * D * 2;       // 6,400,000
    size_t off_Lm = off_Efp8 + (size_t)N_CNT * D;            // 12,800,000 (bf16)
    size_t off_rowptr = off_Lm + (size_t)N_CNT * D * 2;      // 400,128
    size_t off_blkB = off_rowptr + 400128;                   // 2,048
    size_t off_bcnt = off_blkB + 2048;                       // 400,384
    size_t off_part = off_bcnt + 400384;                     // 65,536

    float* all_e = (float*)(ws + off_alle);
    float2* bbuf = (float2*)(ws + off_alle);   // aliases all_e; dead before init_E runs
    unsigned int* packed = (unsigned int*)(ws + off_packed);
    unsigned short* Ebf = (unsigned short*)(ws + off_Ebf);
    unsigned char* Efp8 = (unsigned char*)(ws + off_Efp8);
    unsigned short* Lm = (unsigned short*)(ws + off_Lm);
    int* row_ptr = (int*)(ws + off_rowptr);
    int* blkB = (int*)(ws + off_blkB);
    int* bcnt = (int*)(ws + off_bcnt);
    float4* partials = (float4*)(ws + off_part);

    // bucketed multisplit with exclusive per-(bucket,block) regions
    bucket_hist<<<SC_NBLK, 1024, 0, stream>>>(rows, bcnt);
    scan_p1<<<BCNT_NBLK, 256, 0, stream>>>(bcnt, blkB, BCNT_N);
    scan_p2<<<1, 512, 0, stream>>>(blkB, BCNT_NBLK);
    scan_p3<<<BCNT_NBLK, 256, 0, stream>>>(bcnt, blkB, bcnt, BCNT_N);  // in-place
    block_scatter<<<SC_NBLK, 1024, 0, stream>>>(rows, cols, vals, bcnt, bbuf);
    csr_finalize<<<NBUCKET, 1024, 0, stream>>>(bbuf, bcnt, row_ptr, packed);

    // embeddings (after csr_finalize: bbuf aliases all_e)
    init_E<<<(N_CNT * D) / 256, 256, 0, stream>>>(user_embed, item_embed, Ebf, Efp8, all_e);

    for (int l = 0; l < LAYERS; l++) {
        spmm_fp8<<<(N_CNT * 64) / 256, 256, 0, stream>>>(packed, row_ptr, Efp8, Lm);
        layer_fused_mfma<<<784, 256, 0, stream>>>(Lm, Ebf, Efp8,
                                                  W1 + (size_t)l * 4096, b1 + (size_t)l * 64,
                                                  W2 + (size_t)l * 4096, b2 + (size_t)l * 64,
                                                  all_e, l);
    }

    score_kernel<<<(BATCH * 64) / 256, 256, 0, stream>>>(all_e, users, pos_items, neg_items,
                                                         partials);
    reduce_finalize<<<1, 256, 0, stream>>>(partials, out);
}